// Round 5
// baseline (252.903 us; speedup 1.0000x reference)
//
#include <hip/hip_runtime.h>

typedef unsigned short u16;
typedef unsigned int u32;
typedef u16 u16x4 __attribute__((ext_vector_type(4)));
typedef u16 u16x8 __attribute__((ext_vector_type(8)));
typedef __bf16 bf16x8 __attribute__((ext_vector_type(8)));
typedef float f32x4 __attribute__((ext_vector_type(4)));

#define GPTR(p) (const __attribute__((address_space(1))) void*)(p)
#define LPTR(p) (__attribute__((address_space(3))) void*)(p)
// async global->LDS, 16B per lane; LDS dest = wave-uniform base + lane*16
#define ASYNC16(g, l) __builtin_amdgcn_global_load_lds(GPTR(g), LPTR(l), 16, 0, 0)

// fp32 -> bf16 RTNE (epilogue / non-hot paths)
__device__ __forceinline__ u16 f2bf(float f) {
    u32 u = __builtin_bit_cast(u32, f);
    return (u16)((u + 0x7fffu + ((u >> 16) & 1u)) >> 16);
}
__device__ __forceinline__ bf16x8 ld8(const void* p) {
    return __builtin_bit_cast(bf16x8, *(const u16x8*)p);
}

// ---------------- fp32 -> bf16 conversion ----------------
__global__ void cvt_f32_bf16(const float* __restrict__ in, u16* __restrict__ out, int n4) {
    int i = blockIdx.x * blockDim.x + threadIdx.x;
    if (i >= n4) return;
    float4 v = ((const float4*)in)[i];
    ushort4 o;
    o.x = f2bf(v.x); o.y = f2bf(v.y); o.z = f2bf(v.z); o.w = f2bf(v.w);
    ((ushort4*)out)[i] = o;
}

// ---------------- GEMM: C[m][n] = sum_k A[m][k]*B[n][k]  (B^T input) ----------
template<int MODE>
__global__ __launch_bounds__(256, 2) void gemm_bt(
    const u16* __restrict__ A, const u16* __restrict__ B,
    const float* __restrict__ b0, const float* __restrict__ b1, const float* __restrict__ b2,
    u16* __restrict__ O0, u16* __restrict__ O1, u16* __restrict__ O2,
    float* __restrict__ OF)
{
    constexpr int K = 1024;
    __shared__ __align__(16) u16 As[128 * 32];
    __shared__ __align__(16) u16 Bs[128 * 32];
    const int tid = threadIdx.x;
    const int wave = tid >> 6, lane = tid & 63;
    const int m0 = blockIdx.y * 128, n0 = blockIdx.x * 128;
    const int wm = (wave >> 1) * 64, wn = (wave & 1) * 64;
    const int fr = lane & 15, fg = lane >> 4;

    f32x4 acc[4][4] = {};

    const int srow = lane >> 2;
    const int scol = (lane & 3) * 8;
    const u16* aSrc = A + (size_t)(m0 + wave * 32 + srow) * K + scol;
    const u16* bSrc = B + (size_t)(n0 + wave * 32 + srow) * K + scol;
    u16* const aDst0 = &As[(wave * 32) * 32];
    u16* const aDst1 = &As[(wave * 32 + 16) * 32];
    u16* const bDst0 = &Bs[(wave * 32) * 32];
    u16* const bDst1 = &Bs[(wave * 32 + 16) * 32];

    for (int kt = 0; kt < K; kt += 32) {
        ASYNC16(aSrc + kt,          aDst0);
        ASYNC16(aSrc + kt + 16 * K, aDst1);
        ASYNC16(bSrc + kt,          bDst0);
        ASYNC16(bSrc + kt + 16 * K, bDst1);
        __syncthreads();
        bf16x8 af[4], bfv[4];
        #pragma unroll
        for (int i = 0; i < 4; ++i) af[i]  = ld8(&As[(wm + i * 16 + fr) * 32 + fg * 8]);
        #pragma unroll
        for (int j = 0; j < 4; ++j) bfv[j] = ld8(&Bs[(wn + j * 16 + fr) * 32 + fg * 8]);
        #pragma unroll
        for (int i = 0; i < 4; ++i)
            #pragma unroll
            for (int j = 0; j < 4; ++j)
                acc[i][j] = __builtin_amdgcn_mfma_f32_16x16x32_bf16(af[i], bfv[j], acc[i][j], 0, 0, 0);
        __syncthreads();
    }

    if constexpr (MODE == 0) {
        const float QSCALE = 0.125f * 1.44269504f;
        #pragma unroll
        for (int j = 0; j < 4; ++j) {
            const int n = n0 + wn + j * 16 + fr;
            const int sel = n >> 10;
            const int w = n & 1023;
            const float bb = (sel == 0 ? b0 : sel == 1 ? b1 : b2)[w];
            const float scale = (sel == 0) ? QSCALE : 1.0f;
            u16* const dst = (sel == 0 ? O0 : sel == 1 ? O1 : O2);
            const int h = w >> 6, d = w & 63;
            #pragma unroll
            for (int i = 0; i < 4; ++i) {
                #pragma unroll
                for (int r = 0; r < 4; ++r) {
                    const int m = m0 + wm + i * 16 + fg * 4 + r;
                    const int bi = m >> 11, s = m & 2047;
                    dst[(((size_t)(bi * 16 + h) * 2048 + s) << 6) + d] =
                        f2bf((acc[i][j][r] + bb) * scale);
                }
            }
        }
    } else {
        #pragma unroll
        for (int j = 0; j < 4; ++j) {
            const int n = n0 + wn + j * 16 + fr;
            const float bb = b0[n];
            #pragma unroll
            for (int i = 0; i < 4; ++i) {
                #pragma unroll
                for (int r = 0; r < 4; ++r) {
                    const int m = m0 + wm + i * 16 + fg * 4 + r;
                    OF[(size_t)m * 1024 + n] = acc[i][j][r] + bb;
                }
            }
        }
    }
}

// ---------------- V transpose: [bh][s][64] -> [bh][64][s] (bf16) ----------------
__global__ __launch_bounds__(256) void transpose_v(const u16* __restrict__ Vg, u16* __restrict__ Vt) {
    __shared__ __align__(16) u16 t[64][80];
    const int bh = blockIdx.y;
    const int s0 = blockIdx.x * 64;
    const int tid = threadIdx.x;
    {
        const int sr = tid >> 2, c0 = (tid & 3) * 16;
        const u16* src = Vg + ((size_t)bh * 2048 + s0 + sr) * 64 + c0;
        *(u16x8*)&t[sr][c0]     = *(const u16x8*)src;
        *(u16x8*)&t[sr][c0 + 8] = *(const u16x8*)(src + 8);
    }
    __syncthreads();
    {
        const int d = tid >> 2, s1 = (tid & 3) * 16;
        u16 tmp[16] __attribute__((aligned(16)));
        #pragma unroll
        for (int i = 0; i < 16; ++i) tmp[i] = t[s1 + i][d];
        u16* dst = Vt + ((size_t)bh * 64 + d) * 2048 + s0 + s1;
        *(u16x8*)dst       = *(const u16x8*)&tmp[0];
        *(u16x8*)(dst + 8) = *(const u16x8*)&tmp[8];
    }
}

// ---------------- flash attention: barrier-free, K/V direct from L2 ----------
// Q [bh][s][64] pre-scaled by 0.125*log2e, K [bh][s][64], Vt [bh][64][s],
// masks [b][s] fp32 (binary), out X2 [b][s][h*64+d] bf16.
// All 4 waves previously read IDENTICAL K/V fragments from LDS; instead each
// wave loads them directly from global (L2-hot via XCD swizzle) into regs.
// -> no __syncthreads at all; waves free-run; tile t's PV overlaps tile t+1's
// K loads.  LDS holds only the per-wave P round-trip buffer (8 KB/wave).
// Swapped QK: P = mfma(K,Q) -> D[key][q], q = lane&15 lane-local; packed b64
// P writes / b128 B-operand reads (XOR-swizzled rows).  No-max softmax with
// deferred denominator; mask folded multiplicatively (exact for binary masks).
__global__ __launch_bounds__(256, 2) void attn_fwd(
    const u16* __restrict__ Qg, const u16* __restrict__ Kg, const u16* __restrict__ Vt,
    const float* __restrict__ masks, u16* __restrict__ X2)
{
    __shared__ __align__(16) char smem[32768];   // per-wave P [q=64][key=64] bf16
    const int tid = threadIdx.x;
    const int wave = tid >> 6, lane = tid & 63;

    // bijective XCD swizzle: 512 wgs / 8 XCDs -> 64 contiguous wgs (8 bh) per XCD
    const int bidL = blockIdx.x;
    const int wg = ((bidL & 7) << 6) | (bidL >> 3);
    const int bh = wg >> 3;
    const int q0 = (wg & 7) * 256 + wave * 64;
    const int b = bh >> 4, h = bh & 15;
    const int fr = lane & 15, fg = lane >> 4;
    const int swz = (fr & 7) << 4;

    const u16* const Kbh = Kg + (size_t)bh * 2048 * 64;
    const u16* const Vbh = Vt + (size_t)bh * 64 * 2048;

    // loop-invariant LDS byte addresses (P buffer)
    const int pbase = wave * 8192;
    const int a0 = pbase + fr * 128 + ((fg * 16) ^ swz);
    const int a1 = pbase + fr * 128 + ((64 + fg * 16) ^ swz);
    int pw[4];
    #pragma unroll
    for (int nj = 0; nj < 4; ++nj)
        pw[nj] = pbase + fr * 128 + ((nj * 32 + fg * 8) ^ swz);

    // Q fragments (B-operand): 4 strips of 16 rows
    bf16x8 qf[4][2];
    #pragma unroll
    for (int qs = 0; qs < 4; ++qs) {
        const u16* qp = Qg + ((size_t)bh * 2048 + q0 + qs * 16 + fr) * 64 + fg * 8;
        qf[qs][0] = ld8(qp);
        qf[qs][1] = ld8(qp + 32);
    }

    f32x4 o[4][4] = {};                 // o[dj][qs]: d=dj*16+fg*4+r, q=qs*16+fr
    float psum[4] = {0.f, 0.f, 0.f, 0.f};
    const float* mrow = masks + b * 2048;

    for (int kv0 = 0; kv0 < 2048; kv0 += 64) {
        // issue ALL tile loads upfront: K(8) + V(8) dwordx4 + mask(4) b128.
        // QK waits counted on K; V/mask land under QK+softmax.
        bf16x8 kk[4][2], vv[4][2];
        #pragma unroll
        for (int nj = 0; nj < 4; ++nj) {
            const u16* kp = Kbh + (size_t)(kv0 + nj * 16 + fr) * 64 + fg * 8;
            kk[nj][0] = ld8(kp);
            kk[nj][1] = ld8(kp + 32);
        }
        #pragma unroll
        for (int dj = 0; dj < 4; ++dj) {
            const u16* vp = Vbh + (size_t)(dj * 16 + fr) * 2048 + kv0 + fg * 8;
            vv[dj][0] = ld8(vp);
            vv[dj][1] = ld8(vp + 32);
        }
        float4 mv[4];
        #pragma unroll
        for (int nj = 0; nj < 4; ++nj)
            mv[nj] = *(const float4*)(mrow + kv0 + nj * 16 + fg * 4);

        // QK + softmax + packed P write, per 16-key group
        #pragma unroll
        for (int nj = 0; nj < 4; ++nj) {
            f32x4 s[4];
            __builtin_amdgcn_s_setprio(1);
            #pragma unroll
            for (int qs = 0; qs < 4; ++qs) {
                f32x4 z = {0.f, 0.f, 0.f, 0.f};
                z = __builtin_amdgcn_mfma_f32_16x16x32_bf16(kk[nj][0], qf[qs][0], z, 0, 0, 0);
                s[qs] = __builtin_amdgcn_mfma_f32_16x16x32_bf16(kk[nj][1], qf[qs][1], s[qs] = z, 0, 0, 0);
            }
            __builtin_amdgcn_s_setprio(0);
            #pragma unroll
            for (int qs = 0; qs < 4; ++qs) {
                u16x4 pk;
                #pragma unroll
                for (int r = 0; r < 4; ++r) {
                    const float p = __builtin_exp2f(s[qs][r]) * mv[nj][r];
                    psum[qs] += p;
                    pk[r] = __builtin_bit_cast(u16, (__bf16)p);
                }
                *(u16x4*)(smem + pw[nj] + qs * 2048) = pk;
            }
        }

        // same-wave DS write->read is HW-ordered; block compile-time reorder
        __asm__ volatile("" ::: "memory");
        bf16x8 pa[4][2];
        #pragma unroll
        for (int qs = 0; qs < 4; ++qs) {
            pa[qs][0] = ld8(smem + qs * 2048 + a0);
            pa[qs][1] = ld8(smem + qs * 2048 + a1);
        }

        // PV: o[dj][qs] += mfma(V^T frag, P frag)
        __builtin_amdgcn_s_setprio(1);
        #pragma unroll
        for (int dj = 0; dj < 4; ++dj) {
            #pragma unroll
            for (int qs = 0; qs < 4; ++qs) {
                o[dj][qs] = __builtin_amdgcn_mfma_f32_16x16x32_bf16(vv[dj][0], pa[qs][0], o[dj][qs], 0, 0, 0);
                o[dj][qs] = __builtin_amdgcn_mfma_f32_16x16x32_bf16(vv[dj][1], pa[qs][1], o[dj][qs], 0, 0, 0);
            }
        }
        __builtin_amdgcn_s_setprio(0);
    }

    // deferred denominator: reduce over fg groups (lane bits 4,5)
    #pragma unroll
    for (int qs = 0; qs < 4; ++qs) {
        float s = psum[qs];
        s += __shfl_xor(s, 16, 64);
        s += __shfl_xor(s, 32, 64);
        const float inv = 1.0f / s;
        const int q = q0 + qs * 16 + fr;
        u16* dst = X2 + ((size_t)(b * 2048 + q)) * 1024 + h * 64 + fg * 4;
        #pragma unroll
        for (int dj = 0; dj < 4; ++dj) {
            u16x4 st;
            #pragma unroll
            for (int r = 0; r < 4; ++r) st[r] = f2bf(o[dj][qs][r] * inv);
            *(u16x4*)(dst + dj * 16) = st;
        }
    }
}

// ---------------- launch ----------------
extern "C" void kernel_launch(void* const* d_in, const int* in_sizes, int n_in,
                              void* d_out, int out_size, void* d_ws, size_t ws_size,
                              hipStream_t stream) {
    const float* query = (const float*)d_in[0];
    const float* masks = (const float*)d_in[1];
    const float* Wq = (const float*)d_in[2];
    const float* bq = (const float*)d_in[3];
    const float* Wk = (const float*)d_in[4];
    const float* bk = (const float*)d_in[5];
    const float* Wv = (const float*)d_in[6];
    const float* bv = (const float*)d_in[7];
    const float* Wo = (const float*)d_in[8];
    const float* bo = (const float*)d_in[9];
    float* out = (float*)d_out;

    char* ws = (char*)d_ws;
    u16* Xb   = (u16*)(ws);
    u16* Wcat = (u16*)(ws + (16u << 20));
    u16* Wob  = (u16*)(ws + (22u << 20));
    u16* Qg   = (u16*)(ws + (24u << 20));
    u16* Kg   = (u16*)(ws + (40u << 20));
    u16* Vg   = (u16*)(ws + (56u << 20));
    u16* Vt   = Xb;   // Xb dead after QKV GEMM
    u16* X2   = Vg;   // Vg dead after transpose

    cvt_f32_bf16<<<8192, 256, 0, stream>>>(query, Xb, 8192 * 1024 / 4);
    cvt_f32_bf16<<<1024, 256, 0, stream>>>(Wq, Wcat,               1024 * 1024 / 4);
    cvt_f32_bf16<<<1024, 256, 0, stream>>>(Wk, Wcat + 1024 * 1024, 1024 * 1024 / 4);
    cvt_f32_bf16<<<1024, 256, 0, stream>>>(Wv, Wcat + 2 * 1024 * 1024, 1024 * 1024 / 4);
    cvt_f32_bf16<<<1024, 256, 0, stream>>>(Wo, Wob, 1024 * 1024 / 4);

    gemm_bt<0><<<dim3(24, 64), 256, 0, stream>>>(Xb, Wcat, bq, bk, bv, Qg, Kg, Vg, nullptr);
    transpose_v<<<dim3(32, 64), 256, 0, stream>>>(Vg, Vt);
    attn_fwd<<<512, 256, 0, stream>>>(Qg, Kg, Vt, masks, X2);
    gemm_bt<1><<<dim3(8, 64), 256, 0, stream>>>(X2, Wob, bo, nullptr, nullptr, nullptr,
                                                nullptr, nullptr, out);
}

// Round 6
// 250.093 us; speedup vs baseline: 1.0112x; 1.0112x over previous
//
#include <hip/hip_runtime.h>

typedef unsigned short u16;
typedef unsigned int u32;
typedef u16 u16x4 __attribute__((ext_vector_type(4)));
typedef u16 u16x8 __attribute__((ext_vector_type(8)));
typedef __bf16 bf16x8 __attribute__((ext_vector_type(8)));
typedef float f32x4 __attribute__((ext_vector_type(4)));

#define GPTR(p) (const __attribute__((address_space(1))) void*)(p)
#define LPTR(p) (__attribute__((address_space(3))) void*)(p)
// async global->LDS, 16B per lane; LDS dest = wave-uniform base + lane*16
#define ASYNC16(g, l) __builtin_amdgcn_global_load_lds(GPTR(g), LPTR(l), 16, 0, 0)

// fp32 -> bf16 RTNE (epilogue / non-hot paths)
__device__ __forceinline__ u16 f2bf(float f) {
    u32 u = __builtin_bit_cast(u32, f);
    return (u16)((u + 0x7fffu + ((u >> 16) & 1u)) >> 16);
}
__device__ __forceinline__ bf16x8 ld8(const void* p) {
    return __builtin_bit_cast(bf16x8, *(const u16x8*)p);
}

// ---------------- fp32 -> bf16 conversion ----------------
__global__ void cvt_f32_bf16(const float* __restrict__ in, u16* __restrict__ out, int n4) {
    int i = blockIdx.x * blockDim.x + threadIdx.x;
    if (i >= n4) return;
    float4 v = ((const float4*)in)[i];
    ushort4 o;
    o.x = f2bf(v.x); o.y = f2bf(v.y); o.z = f2bf(v.z); o.w = f2bf(v.w);
    ((ushort4*)out)[i] = o;
}

// ---------------- GEMM: C[m][n] = sum_k A[m][k]*B[n][k]  (B^T input) ----------
template<int MODE>
__global__ __launch_bounds__(256, 2) void gemm_bt(
    const u16* __restrict__ A, const u16* __restrict__ B,
    const float* __restrict__ b0, const float* __restrict__ b1, const float* __restrict__ b2,
    u16* __restrict__ O0, u16* __restrict__ O1, u16* __restrict__ O2,
    float* __restrict__ OF)
{
    constexpr int K = 1024;
    __shared__ __align__(16) u16 As[128 * 32];
    __shared__ __align__(16) u16 Bs[128 * 32];
    const int tid = threadIdx.x;
    const int wave = tid >> 6, lane = tid & 63;
    const int m0 = blockIdx.y * 128, n0 = blockIdx.x * 128;
    const int wm = (wave >> 1) * 64, wn = (wave & 1) * 64;
    const int fr = lane & 15, fg = lane >> 4;

    f32x4 acc[4][4] = {};

    const int srow = lane >> 2;
    const int scol = (lane & 3) * 8;
    const u16* aSrc = A + (size_t)(m0 + wave * 32 + srow) * K + scol;
    const u16* bSrc = B + (size_t)(n0 + wave * 32 + srow) * K + scol;
    u16* const aDst0 = &As[(wave * 32) * 32];
    u16* const aDst1 = &As[(wave * 32 + 16) * 32];
    u16* const bDst0 = &Bs[(wave * 32) * 32];
    u16* const bDst1 = &Bs[(wave * 32 + 16) * 32];

    for (int kt = 0; kt < K; kt += 32) {
        ASYNC16(aSrc + kt,          aDst0);
        ASYNC16(aSrc + kt + 16 * K, aDst1);
        ASYNC16(bSrc + kt,          bDst0);
        ASYNC16(bSrc + kt + 16 * K, bDst1);
        __syncthreads();
        bf16x8 af[4], bfv[4];
        #pragma unroll
        for (int i = 0; i < 4; ++i) af[i]  = ld8(&As[(wm + i * 16 + fr) * 32 + fg * 8]);
        #pragma unroll
        for (int j = 0; j < 4; ++j) bfv[j] = ld8(&Bs[(wn + j * 16 + fr) * 32 + fg * 8]);
        #pragma unroll
        for (int i = 0; i < 4; ++i)
            #pragma unroll
            for (int j = 0; j < 4; ++j)
                acc[i][j] = __builtin_amdgcn_mfma_f32_16x16x32_bf16(af[i], bfv[j], acc[i][j], 0, 0, 0);
        __syncthreads();
    }

    if constexpr (MODE == 0) {
        const float QSCALE = 0.125f * 1.44269504f;
        #pragma unroll
        for (int j = 0; j < 4; ++j) {
            const int n = n0 + wn + j * 16 + fr;
            const int sel = n >> 10;
            const int w = n & 1023;
            const float bb = (sel == 0 ? b0 : sel == 1 ? b1 : b2)[w];
            const float scale = (sel == 0) ? QSCALE : 1.0f;
            u16* const dst = (sel == 0 ? O0 : sel == 1 ? O1 : O2);
            const int h = w >> 6, d = w & 63;
            #pragma unroll
            for (int i = 0; i < 4; ++i) {
                #pragma unroll
                for (int r = 0; r < 4; ++r) {
                    const int m = m0 + wm + i * 16 + fg * 4 + r;
                    const int bi = m >> 11, s = m & 2047;
                    dst[(((size_t)(bi * 16 + h) * 2048 + s) << 6) + d] =
                        f2bf((acc[i][j][r] + bb) * scale);
                }
            }
        }
    } else {
        #pragma unroll
        for (int j = 0; j < 4; ++j) {
            const int n = n0 + wn + j * 16 + fr;
            const float bb = b0[n];
            #pragma unroll
            for (int i = 0; i < 4; ++i) {
                #pragma unroll
                for (int r = 0; r < 4; ++r) {
                    const int m = m0 + wm + i * 16 + fg * 4 + r;
                    OF[(size_t)m * 1024 + n] = acc[i][j][r] + bb;
                }
            }
        }
    }
}

// ---------------- V transpose: [bh][s][64] -> [bh][64][s] (bf16) ----------------
__global__ __launch_bounds__(256) void transpose_v(const u16* __restrict__ Vg, u16* __restrict__ Vt) {
    __shared__ __align__(16) u16 t[64][80];
    const int bh = blockIdx.y;
    const int s0 = blockIdx.x * 64;
    const int tid = threadIdx.x;
    {
        const int sr = tid >> 2, c0 = (tid & 3) * 16;
        const u16* src = Vg + ((size_t)bh * 2048 + s0 + sr) * 64 + c0;
        *(u16x8*)&t[sr][c0]     = *(const u16x8*)src;
        *(u16x8*)&t[sr][c0 + 8] = *(const u16x8*)(src + 8);
    }
    __syncthreads();
    {
        const int d = tid >> 2, s1 = (tid & 3) * 16;
        u16 tmp[16] __attribute__((aligned(16)));
        #pragma unroll
        for (int i = 0; i < 16; ++i) tmp[i] = t[s1 + i][d];
        u16* dst = Vt + ((size_t)bh * 64 + d) * 2048 + s0 + s1;
        *(u16x8*)dst       = *(const u16x8*)&tmp[0];
        *(u16x8*)(dst + 8) = *(const u16x8*)&tmp[8];
    }
}

// ---------------- flash attention: staged K/V, 16 waves/CU ---------------------
// Q [bh][s][64] pre-scaled by 0.125*log2e, K [bh][s][64], Vt [bh][64][s],
// masks [b][s] fp32 (binary), out X2 [b][s][h*64+d] bf16.
// 4 waves x 32 q-rows = 128 q-rows/block -> grid 1024 = 4 blocks/CU; LDS 40 KB
// (K dbuf 16K + V dbuf 16K + per-wave P 2K) -> 16 waves/CU for latency hiding.
// Swapped QK: P = mfma(K,Q) -> D[key][q], q=lane&15 lane-local; P round-trips
// through a per-wave [32 q][32 k] half-buffer (b64 writes / b128 B-reads),
// split into two 32-key halves interleaving QK/softmax/PV.
// No-max softmax, deferred denominator, mask folded multiplicatively.
__global__ __launch_bounds__(256, 4) void attn_fwd(
    const u16* __restrict__ Qg, const u16* __restrict__ Kg, const u16* __restrict__ Vt,
    const float* __restrict__ masks, u16* __restrict__ X2)
{
    // [0,16K) K dbuf, [16K,32K) V dbuf, [32K,40K) P (4 waves x 2K)
    __shared__ __align__(16) char smem[40960];
    const int tid = threadIdx.x;
    const int wave = tid >> 6, lane = tid & 63;

    // bijective XCD swizzle: 1024 wgs / 8 XCDs -> 128 contiguous wgs (8 bh) per XCD
    const int bidL = blockIdx.x;
    const int wg = ((bidL & 7) << 7) | (bidL >> 3);
    const int bh = wg >> 4;                 // 16 q-blocks per bh
    const int q0 = (wg & 15) * 128 + wave * 32;
    const int b = bh >> 4, h = bh & 15;
    const int fr = lane & 15, fg = lane >> 4;
    const int swz  = (fr & 7) << 4;          // K/V 128B-row swizzle (row ≡ fr mod 8)
    const int swz2 = ((fr >> 1) & 3) << 4;   // P 64B-row swizzle

    // loop-invariant LDS byte addresses
    const int a0 = fr * 128 + ((fg * 16) ^ swz);         // K/V read, global cols 0-31
    const int a1 = fr * 128 + ((64 + fg * 16) ^ swz);    // K/V read, global cols 32-63
    const int pbase = 32768 + wave * 2048;               // P [32 q][32 k] bf16
    const int pr  = pbase + fr * 64 + ((fg * 16) ^ swz2);          // P read (B-op)
    const int pw0 = pbase + fr * 64 + ((fg * 8) ^ swz2);           // P write njl=0
    const int pw1 = pbase + fr * 64 + ((32 + fg * 8) ^ swz2);      // P write njl=1

    // Q fragments (B-operand): 2 strips of 16 rows
    bf16x8 qf[2][2];
    #pragma unroll
    for (int qs = 0; qs < 2; ++qs) {
        const u16* qp = Qg + ((size_t)bh * 2048 + q0 + qs * 16 + fr) * 64 + fg * 8;
        qf[qs][0] = ld8(qp);
        qf[qs][1] = ld8(qp + 32);
    }

    f32x4 o[4][2] = {};                 // o[dj][qs]: d=dj*16+fg*4+r, q=qs*16+fr
    float psum[2] = {0.f, 0.f};

    const int srow = lane >> 3;
    const int scb = (lane & 7) * 16;
    const float* mrow = masks + b * 2048;

    auto STAGE = [&](int buf, int kv0) {
        #pragma unroll
        for (int j = 0; j < 2; ++j) {
            const int r0 = wave * 16 + j * 8;
            const int row = r0 + srow;
            const int sw = scb ^ ((row & 7) << 4);
            ASYNC16((const char*)(Kg + ((size_t)bh * 2048 + kv0 + row) * 64) + sw,
                    smem + buf * 8192 + r0 * 128);
            ASYNC16((const char*)(Vt + ((size_t)bh * 64 + row) * 2048 + kv0) + sw,
                    smem + 16384 + buf * 8192 + r0 * 128);
        }
    };

    STAGE(0, 0);
    for (int kvb = 0; kvb < 2048; kvb += 128) {
        #pragma unroll
        for (int half = 0; half < 2; ++half) {
            const int kv = kvb + half * 64;
            const int kb = half * 8192;            // compile-time dbuf bases
            const int vb = 16384 + half * 8192;
            __syncthreads();                        // buf[half] staged
            if (kv + 64 < 2048) STAGE(half ^ 1, kv + 64);

            // mask values: key = nj*16 + fg*4 + r (L1/L2-hot)
            float4 mv[4];
            #pragma unroll
            for (int nj = 0; nj < 4; ++nj)
                mv[nj] = *(const float4*)(mrow + kv + nj * 16 + fg * 4);

            // two 32-key halves: QK -> softmax -> P round-trip -> PV
            #pragma unroll
            for (int hh = 0; hh < 2; ++hh) {
                f32x4 s[2][2];                       // [njl][qs]
                #pragma unroll
                for (int njl = 0; njl < 2; ++njl) {
                    const int nj = hh * 2 + njl;
                    bf16x8 k0 = ld8(smem + kb + nj * 2048 + a0);
                    bf16x8 k1 = ld8(smem + kb + nj * 2048 + a1);
                    __builtin_amdgcn_s_setprio(1);
                    #pragma unroll
                    for (int qs = 0; qs < 2; ++qs) {
                        f32x4 z = {0.f, 0.f, 0.f, 0.f};
                        z = __builtin_amdgcn_mfma_f32_16x16x32_bf16(k0, qf[qs][0], z, 0, 0, 0);
                        s[njl][qs] = __builtin_amdgcn_mfma_f32_16x16x32_bf16(k1, qf[qs][1], z, 0, 0, 0);
                    }
                    __builtin_amdgcn_s_setprio(0);
                }
                #pragma unroll
                for (int njl = 0; njl < 2; ++njl) {
                    const int nj = hh * 2 + njl;
                    const int pw = njl ? pw1 : pw0;
                    #pragma unroll
                    for (int qs = 0; qs < 2; ++qs) {
                        u16x4 pk;
                        #pragma unroll
                        for (int r = 0; r < 4; ++r) {
                            const float p = __builtin_exp2f(s[njl][qs][r]) * mv[nj][r];
                            psum[qs] += p;
                            pk[r] = __builtin_bit_cast(u16, (__bf16)p);
                        }
                        *(u16x4*)(smem + pw + qs * 1024) = pk;
                    }
                }

                // same-wave DS write->read is HW-ordered; block compile-time reorder
                __asm__ volatile("" ::: "memory");
                bf16x8 pa0 = ld8(smem + pr);
                bf16x8 pa1 = ld8(smem + pr + 1024);
                __asm__ volatile("" ::: "memory");

                // PV for keys hh*32..hh*32+31 (V byte-half hh)
                __builtin_amdgcn_s_setprio(1);
                #pragma unroll
                for (int dj = 0; dj < 4; ++dj) {
                    bf16x8 v = ld8(smem + vb + dj * 2048 + (hh ? a1 : a0));
                    o[dj][0] = __builtin_amdgcn_mfma_f32_16x16x32_bf16(v, pa0, o[dj][0], 0, 0, 0);
                    o[dj][1] = __builtin_amdgcn_mfma_f32_16x16x32_bf16(v, pa1, o[dj][1], 0, 0, 0);
                }
                __builtin_amdgcn_s_setprio(0);
            }
        }
    }

    // deferred denominator: reduce over fg groups (lane bits 4,5)
    #pragma unroll
    for (int qs = 0; qs < 2; ++qs) {
        float s = psum[qs];
        s += __shfl_xor(s, 16, 64);
        s += __shfl_xor(s, 32, 64);
        const float inv = 1.0f / s;
        const int q = q0 + qs * 16 + fr;
        u16* dst = X2 + ((size_t)(b * 2048 + q)) * 1024 + h * 64 + fg * 4;
        #pragma unroll
        for (int dj = 0; dj < 4; ++dj) {
            u16x4 st;
            #pragma unroll
            for (int r = 0; r < 4; ++r) st[r] = f2bf(o[dj][qs][r] * inv);
            *(u16x4*)(dst + dj * 16) = st;
        }
    }
}

// ---------------- launch ----------------
extern "C" void kernel_launch(void* const* d_in, const int* in_sizes, int n_in,
                              void* d_out, int out_size, void* d_ws, size_t ws_size,
                              hipStream_t stream) {
    const float* query = (const float*)d_in[0];
    const float* masks = (const float*)d_in[1];
    const float* Wq = (const float*)d_in[2];
    const float* bq = (const float*)d_in[3];
    const float* Wk = (const float*)d_in[4];
    const float* bk = (const float*)d_in[5];
    const float* Wv = (const float*)d_in[6];
    const float* bv = (const float*)d_in[7];
    const float* Wo = (const float*)d_in[8];
    const float* bo = (const float*)d_in[9];
    float* out = (float*)d_out;

    char* ws = (char*)d_ws;
    u16* Xb   = (u16*)(ws);
    u16* Wcat = (u16*)(ws + (16u << 20));
    u16* Wob  = (u16*)(ws + (22u << 20));
    u16* Qg   = (u16*)(ws + (24u << 20));
    u16* Kg   = (u16*)(ws + (40u << 20));
    u16* Vg   = (u16*)(ws + (56u << 20));
    u16* Vt   = Xb;   // Xb dead after QKV GEMM
    u16* X2   = Vg;   // Vg dead after transpose

    cvt_f32_bf16<<<8192, 256, 0, stream>>>(query, Xb, 8192 * 1024 / 4);
    cvt_f32_bf16<<<1024, 256, 0, stream>>>(Wq, Wcat,               1024 * 1024 / 4);
    cvt_f32_bf16<<<1024, 256, 0, stream>>>(Wk, Wcat + 1024 * 1024, 1024 * 1024 / 4);
    cvt_f32_bf16<<<1024, 256, 0, stream>>>(Wv, Wcat + 2 * 1024 * 1024, 1024 * 1024 / 4);
    cvt_f32_bf16<<<1024, 256, 0, stream>>>(Wo, Wob, 1024 * 1024 / 4);

    gemm_bt<0><<<dim3(24, 64), 256, 0, stream>>>(Xb, Wcat, bq, bk, bv, Qg, Kg, Vg, nullptr);
    transpose_v<<<dim3(32, 64), 256, 0, stream>>>(Vg, Vt);
    attn_fwd<<<1024, 256, 0, stream>>>(Qg, Kg, Vt, masks, X2);
    gemm_bt<1><<<dim3(8, 64), 256, 0, stream>>>(X2, Wob, bo, nullptr, nullptr, nullptr,
                                                nullptr, nullptr, out);
}

// Round 7
// 228.306 us; speedup vs baseline: 1.1077x; 1.0954x over previous
//
#include <hip/hip_runtime.h>

typedef unsigned short u16;
typedef unsigned int u32;
typedef u16 u16x4 __attribute__((ext_vector_type(4)));
typedef u16 u16x8 __attribute__((ext_vector_type(8)));
typedef __bf16 bf16x8 __attribute__((ext_vector_type(8)));
typedef float f32x4 __attribute__((ext_vector_type(4)));

#define GPTR(p) (const __attribute__((address_space(1))) void*)(p)
#define LPTR(p) (__attribute__((address_space(3))) void*)(p)
// async global->LDS, 16B per lane; LDS dest = wave-uniform base + lane*16
#define ASYNC16(g, l) __builtin_amdgcn_global_load_lds(GPTR(g), LPTR(l), 16, 0, 0)

// fp32 -> bf16 RTNE (epilogue / non-hot paths)
__device__ __forceinline__ u16 f2bf(float f) {
    u32 u = __builtin_bit_cast(u32, f);
    return (u16)((u + 0x7fffu + ((u >> 16) & 1u)) >> 16);
}
__device__ __forceinline__ bf16x8 ld8(const void* p) {
    return __builtin_bit_cast(bf16x8, *(const u16x8*)p);
}

// ---------------- fp32 -> bf16 conversion ----------------
__global__ void cvt_f32_bf16(const float* __restrict__ in, u16* __restrict__ out, int n4) {
    int i = blockIdx.x * blockDim.x + threadIdx.x;
    if (i >= n4) return;
    float4 v = ((const float4*)in)[i];
    ushort4 o;
    o.x = f2bf(v.x); o.y = f2bf(v.y); o.z = f2bf(v.z); o.w = f2bf(v.w);
    ((ushort4*)out)[i] = o;
}

// ---------------- GEMM: C[m][n] = sum_k A[m][k]*B[n][k]  (B^T input) ----------
// MODE 0: QKV fused (N=3072): out = (C + bias[n]) * (n<1024 ? QSCALE : 1).
//   Q,K -> [b][h][s][64] bf16;  V -> TRANSPOSED [b][h][64][s] bf16 (fuses the
//   old transpose_v pass; r-loop gives s-consecutive u16x4 stores).
// MODE 1: out-proj (N=1024): OF[m][n] = C + b0[n]  (fp32)
template<int MODE>
__global__ __launch_bounds__(256, 2) void gemm_bt(
    const u16* __restrict__ A, const u16* __restrict__ B,
    const float* __restrict__ b0, const float* __restrict__ b1, const float* __restrict__ b2,
    u16* __restrict__ O0, u16* __restrict__ O1, u16* __restrict__ O2,
    float* __restrict__ OF)
{
    constexpr int K = 1024;
    __shared__ __align__(16) u16 As[128 * 32];
    __shared__ __align__(16) u16 Bs[128 * 32];
    const int tid = threadIdx.x;
    const int wave = tid >> 6, lane = tid & 63;
    const int m0 = blockIdx.y * 128, n0 = blockIdx.x * 128;
    const int wm = (wave >> 1) * 64, wn = (wave & 1) * 64;
    const int fr = lane & 15, fg = lane >> 4;

    f32x4 acc[4][4] = {};

    const int srow = lane >> 2;
    const int scol = (lane & 3) * 8;
    const u16* aSrc = A + (size_t)(m0 + wave * 32 + srow) * K + scol;
    const u16* bSrc = B + (size_t)(n0 + wave * 32 + srow) * K + scol;
    u16* const aDst0 = &As[(wave * 32) * 32];
    u16* const aDst1 = &As[(wave * 32 + 16) * 32];
    u16* const bDst0 = &Bs[(wave * 32) * 32];
    u16* const bDst1 = &Bs[(wave * 32 + 16) * 32];

    for (int kt = 0; kt < K; kt += 32) {
        ASYNC16(aSrc + kt,          aDst0);
        ASYNC16(aSrc + kt + 16 * K, aDst1);
        ASYNC16(bSrc + kt,          bDst0);
        ASYNC16(bSrc + kt + 16 * K, bDst1);
        __syncthreads();
        bf16x8 af[4], bfv[4];
        #pragma unroll
        for (int i = 0; i < 4; ++i) af[i]  = ld8(&As[(wm + i * 16 + fr) * 32 + fg * 8]);
        #pragma unroll
        for (int j = 0; j < 4; ++j) bfv[j] = ld8(&Bs[(wn + j * 16 + fr) * 32 + fg * 8]);
        #pragma unroll
        for (int i = 0; i < 4; ++i)
            #pragma unroll
            for (int j = 0; j < 4; ++j)
                acc[i][j] = __builtin_amdgcn_mfma_f32_16x16x32_bf16(af[i], bfv[j], acc[i][j], 0, 0, 0);
        __syncthreads();
    }

    if constexpr (MODE == 0) {
        const float QSCALE = 0.125f * 1.44269504f;   // 1/sqrt(64) * log2(e)
        #pragma unroll
        for (int j = 0; j < 4; ++j) {
            const int n = n0 + wn + j * 16 + fr;
            const int sel = n >> 10;          // 0=Q 1=K 2=V (uniform per fragment)
            const int w = n & 1023;
            const float bb = (sel == 0 ? b0 : sel == 1 ? b1 : b2)[w];
            const int h = w >> 6, d = w & 63;
            if (sel == 2) {
                // V transposed: Vt[(bi*16+h)*64 + d][s], s-consecutive -> u16x4
                #pragma unroll
                for (int i = 0; i < 4; ++i) {
                    const int m = m0 + wm + i * 16 + fg * 4;   // s base (4-aligned)
                    u16x4 st;
                    #pragma unroll
                    for (int r = 0; r < 4; ++r) st[r] = f2bf(acc[i][j][r] + bb);
                    *(u16x4*)&O2[((size_t)(((m >> 11) * 16 + h) * 64 + d)) * 2048 + (m & 2047)] = st;
                }
            } else {
                const float scale = (sel == 0) ? QSCALE : 1.0f;
                u16* const dst = (sel == 0 ? O0 : O1);
                #pragma unroll
                for (int i = 0; i < 4; ++i) {
                    #pragma unroll
                    for (int r = 0; r < 4; ++r) {
                        const int m = m0 + wm + i * 16 + fg * 4 + r;
                        dst[(((size_t)((m >> 11) * 16 + h) * 2048 + (m & 2047)) << 6) + d] =
                            f2bf((acc[i][j][r] + bb) * scale);
                    }
                }
            }
        }
    } else {
        #pragma unroll
        for (int j = 0; j < 4; ++j) {
            const int n = n0 + wn + j * 16 + fr;
            const float bb = b0[n];
            #pragma unroll
            for (int i = 0; i < 4; ++i) {
                #pragma unroll
                for (int r = 0; r < 4; ++r) {
                    const int m = m0 + wm + i * 16 + fg * 4 + r;
                    OF[(size_t)m * 1024 + n] = acc[i][j][r] + bb;
                }
            }
        }
    }
}

// ---------------- flash attention: R4 structure + phase decorrelation ---------
// Q [bh][s][64] pre-scaled by 0.125*log2e, K [bh][s][64], Vt [bh][64][s],
// masks [b][s] fp32 (binary), out X2 [b][s][h*64+d] bf16.
// 4 waves x 64 q-rows; KVBLK=64 double-buffered; 1 barrier/tile.
// Co-resident blocks (p, p+256) start 16 kv-tiles apart (key order commutes
// with no-max softmax + deferred denominator) -> VALU/DS/MFMA bursts interleave
// across blocks instead of colliding.
// Within-tile: key-halves pipelined in ISSUE order QKh0-smh0-PVh0-QKh1-smh1-PVh1
// so sm VALU executes while 32 issued MFMAs drain.
// smem 64KB: K dbuf [0,16K), V dbuf [16K,32K), P per-wave [32K,64K).
__global__ __launch_bounds__(256, 2) void attn_fwd(
    const u16* __restrict__ Qg, const u16* __restrict__ Kg, const u16* __restrict__ Vt,
    const float* __restrict__ masks, u16* __restrict__ X2)
{
    __shared__ __align__(16) char smem[65536];
    const int tid = threadIdx.x;
    const int wave = tid >> 6, lane = tid & 63;

    // bijective XCD swizzle: 512 wgs / 8 XCDs -> 64 contiguous wgs (8 bh) per XCD
    const int bidL = blockIdx.x;
    const int wg = ((bidL & 7) << 6) | (bidL >> 3);
    const int bh = wg >> 3;
    const int q0 = (wg & 7) * 256 + wave * 64;
    const int b = bh >> 4, h = bh & 15;
    const int fr = lane & 15, fg = lane >> 4;
    const int swz = (fr & 7) << 4;

    // loop-invariant LDS byte addresses
    const int a0 = fr * 128 + ((fg * 16) ^ swz);          // frag low 64B (k/d 0-31)
    const int a1 = fr * 128 + ((64 + fg * 16) ^ swz);     // frag high 64B
    const int pbase = 32768 + wave * 8192;                // P [64 q][64 k] bf16
    int pw[4];
    #pragma unroll
    for (int nj = 0; nj < 4; ++nj)
        pw[nj] = pbase + fr * 128 + ((nj * 32 + fg * 8) ^ swz);

    // Q fragments (B-operand): 4 strips of 16 rows
    bf16x8 qf[4][2];
    #pragma unroll
    for (int qs = 0; qs < 4; ++qs) {
        const u16* qp = Qg + ((size_t)bh * 2048 + q0 + qs * 16 + fr) * 64 + fg * 8;
        qf[qs][0] = ld8(qp);
        qf[qs][1] = ld8(qp + 32);
    }

    f32x4 o[4][4] = {};                 // o[dj][qs]: d=dj*16+fg*4+r, q=qs*16+fr
    float psum[4] = {0.f, 0.f, 0.f, 0.f};

    const int srow = lane >> 3;
    const int scb = (lane & 7) * 16;
    const float* mrow = masks + b * 2048;

    auto STAGE = [&](int buf, int kv0) {
        #pragma unroll
        for (int j = 0; j < 2; ++j) {
            const int r0 = wave * 16 + j * 8;
            const int row = r0 + srow;
            const int sw = scb ^ ((row & 7) << 4);
            ASYNC16((const char*)(Kg + ((size_t)bh * 2048 + kv0 + row) * 64) + sw,
                    smem + buf * 8192 + r0 * 128);
            ASYNC16((const char*)(Vt + ((size_t)bh * 64 + row) * 2048 + kv0) + sw,
                    smem + 16384 + buf * 8192 + r0 * 128);
        }
    };

    const int t0 = ((bidL >> 8) & 1) << 4;   // co-resident blocks start 16 tiles apart
    STAGE(0, t0 * 64);
    for (int it = 0; it < 32; it += 2) {
        #pragma unroll
        for (int half = 0; half < 2; ++half) {
            const int tile = (t0 + it + half) & 31;
            const int kv = tile * 64;
            const int kb = half * 8192;            // compile-time dbuf bases
            const int vb = 16384 + half * 8192;
            __syncthreads();                        // buf[half] staged
            if (it + half < 31) STAGE(half ^ 1, ((tile + 1) & 31) * 64);

            float4 mv[4];
            #pragma unroll
            for (int nj = 0; nj < 4; ++nj)
                mv[nj] = *(const float4*)(mrow + kv + nj * 16 + fg * 4);

            // per key-half: QK (issue) -> softmax -> P write/read -> PV (issue)
            // next half's QK issues before this half's PV drains; sm VALU overlaps.
            #pragma unroll
            for (int hh = 0; hh < 2; ++hh) {
                const int aK = hh ? a1 : a0;        // V/P frag byte-half for this hh
                f32x4 s[2][4];
                #pragma unroll
                for (int njl = 0; njl < 2; ++njl) {
                    const int nj = hh * 2 + njl;
                    bf16x8 k0 = ld8(smem + kb + nj * 2048 + a0);
                    bf16x8 k1 = ld8(smem + kb + nj * 2048 + a1);
                    __builtin_amdgcn_s_setprio(1);
                    #pragma unroll
                    for (int qs = 0; qs < 4; ++qs) {
                        f32x4 z = {0.f, 0.f, 0.f, 0.f};
                        z = __builtin_amdgcn_mfma_f32_16x16x32_bf16(k0, qf[qs][0], z, 0, 0, 0);
                        s[njl][qs] = __builtin_amdgcn_mfma_f32_16x16x32_bf16(k1, qf[qs][1], z, 0, 0, 0);
                    }
                    __builtin_amdgcn_s_setprio(0);
                }
                #pragma unroll
                for (int njl = 0; njl < 2; ++njl) {
                    const int nj = hh * 2 + njl;
                    #pragma unroll
                    for (int qs = 0; qs < 4; ++qs) {
                        u16x4 pk;
                        #pragma unroll
                        for (int r = 0; r < 4; ++r) {
                            const float p = __builtin_exp2f(s[njl][qs][r]) * mv[nj][r];
                            psum[qs] += p;
                            pk[r] = __builtin_bit_cast(u16, (__bf16)p);
                        }
                        *(u16x4*)(smem + pw[nj] + qs * 2048) = pk;
                    }
                }

                // same-wave DS write->read is HW-ordered; block compile-time reorder
                __asm__ volatile("" ::: "memory");
                bf16x8 pa[4];
                #pragma unroll
                for (int qs = 0; qs < 4; ++qs)
                    pa[qs] = ld8(smem + pbase + qs * 2048 + aK);

                __builtin_amdgcn_s_setprio(1);
                #pragma unroll
                for (int dj = 0; dj < 4; ++dj) {
                    bf16x8 v = ld8(smem + vb + dj * 2048 + aK);
                    #pragma unroll
                    for (int qs = 0; qs < 4; ++qs)
                        o[dj][qs] = __builtin_amdgcn_mfma_f32_16x16x32_bf16(v, pa[qs], o[dj][qs], 0, 0, 0);
                }
                __builtin_amdgcn_s_setprio(0);
            }
        }
    }

    // deferred denominator: reduce over fg groups (lane bits 4,5)
    #pragma unroll
    for (int qs = 0; qs < 4; ++qs) {
        float s = psum[qs];
        s += __shfl_xor(s, 16, 64);
        s += __shfl_xor(s, 32, 64);
        const float inv = 1.0f / s;
        const int q = q0 + qs * 16 + fr;
        u16* dst = X2 + ((size_t)(b * 2048 + q)) * 1024 + h * 64 + fg * 4;
        #pragma unroll
        for (int dj = 0; dj < 4; ++dj) {
            u16x4 st;
            #pragma unroll
            for (int r = 0; r < 4; ++r) st[r] = f2bf(o[dj][qs][r] * inv);
            *(u16x4*)(dst + dj * 16) = st;
        }
    }
}

// ---------------- launch ----------------
extern "C" void kernel_launch(void* const* d_in, const int* in_sizes, int n_in,
                              void* d_out, int out_size, void* d_ws, size_t ws_size,
                              hipStream_t stream) {
    const float* query = (const float*)d_in[0];
    const float* masks = (const float*)d_in[1];
    const float* Wq = (const float*)d_in[2];
    const float* bq = (const float*)d_in[3];
    const float* Wk = (const float*)d_in[4];
    const float* bk = (const float*)d_in[5];
    const float* Wv = (const float*)d_in[6];
    const float* bv = (const float*)d_in[7];
    const float* Wo = (const float*)d_in[8];
    const float* bo = (const float*)d_in[9];
    float* out = (float*)d_out;

    // workspace (72 MB):
    //  [ 0,16M): Xb (bf16 query)  -> reused as X2 (attn out) after QKV GEMM
    //  [16,22M): Wcat  [22,24M): Wob
    //  [24,40M): Qg   [40,56M): Kg   [56,72M): Vt (written transposed by GEMM)
    char* ws = (char*)d_ws;
    u16* Xb   = (u16*)(ws);
    u16* Wcat = (u16*)(ws + (16u << 20));
    u16* Wob  = (u16*)(ws + (22u << 20));
    u16* Qg   = (u16*)(ws + (24u << 20));
    u16* Kg   = (u16*)(ws + (40u << 20));
    u16* Vt   = (u16*)(ws + (56u << 20));
    u16* X2   = Xb;   // Xb dead after QKV GEMM

    cvt_f32_bf16<<<8192, 256, 0, stream>>>(query, Xb, 8192 * 1024 / 4);
    cvt_f32_bf16<<<1024, 256, 0, stream>>>(Wq, Wcat,               1024 * 1024 / 4);
    cvt_f32_bf16<<<1024, 256, 0, stream>>>(Wk, Wcat + 1024 * 1024, 1024 * 1024 / 4);
    cvt_f32_bf16<<<1024, 256, 0, stream>>>(Wv, Wcat + 2 * 1024 * 1024, 1024 * 1024 / 4);
    cvt_f32_bf16<<<1024, 256, 0, stream>>>(Wo, Wob, 1024 * 1024 / 4);

    gemm_bt<0><<<dim3(24, 64), 256, 0, stream>>>(Xb, Wcat, bq, bk, bv, Qg, Kg, Vt, nullptr);
    attn_fwd<<<512, 256, 0, stream>>>(Qg, Kg, Vt, masks, X2);
    gemm_bt<1><<<dim3(8, 64), 256, 0, stream>>>(X2, Wob, bo, nullptr, nullptr, nullptr,
                                                nullptr, nullptr, out);
}

// Round 8
// 226.547 us; speedup vs baseline: 1.1163x; 1.0078x over previous
//
#include <hip/hip_runtime.h>

typedef unsigned short u16;
typedef unsigned int u32;
typedef u16 u16x4 __attribute__((ext_vector_type(4)));
typedef u16 u16x8 __attribute__((ext_vector_type(8)));
typedef u32 u32x4 __attribute__((ext_vector_type(4)));
typedef __bf16 bf16x8 __attribute__((ext_vector_type(8)));
typedef float f32x4 __attribute__((ext_vector_type(4)));

#define GPTR(p) (const __attribute__((address_space(1))) void*)(p)
#define LPTR(p) (__attribute__((address_space(3))) void*)(p)
// async global->LDS, 16B per lane; LDS dest = wave-uniform base + lane*16
#define ASYNC16(g, l) __builtin_amdgcn_global_load_lds(GPTR(g), LPTR(l), 16, 0, 0)

// fp32 -> bf16 RTNE (epilogue / non-hot paths)
__device__ __forceinline__ u16 f2bf(float f) {
    u32 u = __builtin_bit_cast(u32, f);
    return (u16)((u + 0x7fffu + ((u >> 16) & 1u)) >> 16);
}
__device__ __forceinline__ bf16x8 ld8(const void* p) {
    return __builtin_bit_cast(bf16x8, *(const u16x8*)p);
}

// ---------------- fp32 -> bf16 conversion ----------------
__global__ void cvt_f32_bf16(const float* __restrict__ in, u16* __restrict__ out, int n4) {
    int i = blockIdx.x * blockDim.x + threadIdx.x;
    if (i >= n4) return;
    float4 v = ((const float4*)in)[i];
    ushort4 o;
    o.x = f2bf(v.x); o.y = f2bf(v.y); o.z = f2bf(v.z); o.w = f2bf(v.w);
    ((ushort4*)out)[i] = o;
}

// ---------------- GEMM: C[m][n] = sum_k A[m][k]*B[n][k]  (B^T input) ----------
// MODE 0: QKV fused (N=3072): out = (C + bias[n]) * (n<1024 ? QSCALE : 1).
//   Q,K -> [b][h][s][64] bf16;  V -> TRANSPOSED [b][h][64][s] bf16.
// MODE 1: out-proj (N=1024): OF[m][n] = C + b0[n]  (fp32)
template<int MODE>
__global__ __launch_bounds__(256, 2) void gemm_bt(
    const u16* __restrict__ A, const u16* __restrict__ B,
    const float* __restrict__ b0, const float* __restrict__ b1, const float* __restrict__ b2,
    u16* __restrict__ O0, u16* __restrict__ O1, u16* __restrict__ O2,
    float* __restrict__ OF)
{
    constexpr int K = 1024;
    __shared__ __align__(16) u16 As[128 * 32];
    __shared__ __align__(16) u16 Bs[128 * 32];
    const int tid = threadIdx.x;
    const int wave = tid >> 6, lane = tid & 63;
    const int m0 = blockIdx.y * 128, n0 = blockIdx.x * 128;
    const int wm = (wave >> 1) * 64, wn = (wave & 1) * 64;
    const int fr = lane & 15, fg = lane >> 4;

    f32x4 acc[4][4] = {};

    const int srow = lane >> 2;
    const int scol = (lane & 3) * 8;
    const u16* aSrc = A + (size_t)(m0 + wave * 32 + srow) * K + scol;
    const u16* bSrc = B + (size_t)(n0 + wave * 32 + srow) * K + scol;
    u16* const aDst0 = &As[(wave * 32) * 32];
    u16* const aDst1 = &As[(wave * 32 + 16) * 32];
    u16* const bDst0 = &Bs[(wave * 32) * 32];
    u16* const bDst1 = &Bs[(wave * 32 + 16) * 32];

    for (int kt = 0; kt < K; kt += 32) {
        ASYNC16(aSrc + kt,          aDst0);
        ASYNC16(aSrc + kt + 16 * K, aDst1);
        ASYNC16(bSrc + kt,          bDst0);
        ASYNC16(bSrc + kt + 16 * K, bDst1);
        __syncthreads();
        bf16x8 af[4], bfv[4];
        #pragma unroll
        for (int i = 0; i < 4; ++i) af[i]  = ld8(&As[(wm + i * 16 + fr) * 32 + fg * 8]);
        #pragma unroll
        for (int j = 0; j < 4; ++j) bfv[j] = ld8(&Bs[(wn + j * 16 + fr) * 32 + fg * 8]);
        #pragma unroll
        for (int i = 0; i < 4; ++i)
            #pragma unroll
            for (int j = 0; j < 4; ++j)
                acc[i][j] = __builtin_amdgcn_mfma_f32_16x16x32_bf16(af[i], bfv[j], acc[i][j], 0, 0, 0);
        __syncthreads();
    }

    if constexpr (MODE == 0) {
        const float QSCALE = 0.125f * 1.44269504f;   // 1/sqrt(64) * log2(e)
        #pragma unroll
        for (int j = 0; j < 4; ++j) {
            const int n = n0 + wn + j * 16 + fr;
            const int sel = n >> 10;          // 0=Q 1=K 2=V (uniform per fragment)
            const int w = n & 1023;
            const float bb = (sel == 0 ? b0 : sel == 1 ? b1 : b2)[w];
            const int h = w >> 6, d = w & 63;
            if (sel == 2) {
                // V transposed: Vt[(bi*16+h)*64 + d][s], s-consecutive -> u16x4
                #pragma unroll
                for (int i = 0; i < 4; ++i) {
                    const int m = m0 + wm + i * 16 + fg * 4;   // s base (4-aligned)
                    u16x4 st;
                    #pragma unroll
                    for (int r = 0; r < 4; ++r) st[r] = f2bf(acc[i][j][r] + bb);
                    *(u16x4*)&O2[((size_t)(((m >> 11) * 16 + h) * 64 + d)) * 2048 + (m & 2047)] = st;
                }
            } else {
                const float scale = (sel == 0) ? QSCALE : 1.0f;
                u16* const dst = (sel == 0 ? O0 : O1);
                #pragma unroll
                for (int i = 0; i < 4; ++i) {
                    #pragma unroll
                    for (int r = 0; r < 4; ++r) {
                        const int m = m0 + wm + i * 16 + fg * 4 + r;
                        dst[(((size_t)((m >> 11) * 16 + h) * 2048 + (m & 2047)) << 6) + d] =
                            f2bf((acc[i][j][r] + bb) * scale);
                    }
                }
            }
        }
    } else {
        #pragma unroll
        for (int j = 0; j < 4; ++j) {
            const int n = n0 + wn + j * 16 + fr;
            const float bb = b0[n];
            #pragma unroll
            for (int i = 0; i < 4; ++i) {
                #pragma unroll
                for (int r = 0; r < 4; ++r) {
                    const int m = m0 + wm + i * 16 + fg * 4 + r;
                    OF[(size_t)m * 1024 + n] = acc[i][j][r] + bb;
                }
            }
        }
    }
}

// ---------------- flash attention: in-register P (no LDS round-trip) ----------
// Q [bh][s][64] pre-scaled by 0.125*log2e, K [bh][s][64], Vt [bh][64][s],
// masks [b][s] fp32 (binary), out X2 [b][s][h*64+d] bf16.
// 4 waves x 64 q-rows; KVBLK=64 double-buffered; 1 barrier/tile.
// Swapped QK: P = mfma(K,Q) -> lane(fr,fg) holds P[key=nj*16+fg*4+r][q=fr].
// PV B-operand needs keys fg*8+e.  In (lane-bit5, lane-bit4, word-bit1,
// word-bit0) index space the needed permutation = swap(L5,W1) then swap(L4,W1):
//   v_permlane32_swap_b32 (dst-hi-lanes <-> src-lo-lanes  == swap(L5, word))
//   v_permlane16_swap_b32 (odd 16-rows  <-> even 16-rows  == swap(L4, word))
// 4 cvt_pk + 4 permlane per qs replace 4 ds_write_b64 + 2 ds_read_b128 + fences.
// No-max softmax, deferred denominator, mask folded multiplicatively.
// smem 32KB: K dbuf [0,16K), V dbuf [16K,32K).
__global__ __launch_bounds__(256, 2) void attn_fwd(
    const u16* __restrict__ Qg, const u16* __restrict__ Kg, const u16* __restrict__ Vt,
    const float* __restrict__ masks, u16* __restrict__ X2)
{
    __shared__ __align__(16) char smem[32768];
    const int tid = threadIdx.x;
    const int wave = tid >> 6, lane = tid & 63;

    // bijective XCD swizzle: 512 wgs / 8 XCDs -> 64 contiguous wgs (8 bh) per XCD
    const int bidL = blockIdx.x;
    const int wg = ((bidL & 7) << 6) | (bidL >> 3);
    const int bh = wg >> 3;
    const int q0 = (wg & 7) * 256 + wave * 64;
    const int b = bh >> 4, h = bh & 15;
    const int fr = lane & 15, fg = lane >> 4;
    const int swz = (fr & 7) << 4;

    // loop-invariant LDS byte addresses
    const int a0 = fr * 128 + ((fg * 16) ^ swz);          // frag low 64B (k/d 0-31)
    const int a1 = fr * 128 + ((64 + fg * 16) ^ swz);     // frag high 64B

    // Q fragments (B-operand): 4 strips of 16 rows
    bf16x8 qf[4][2];
    #pragma unroll
    for (int qs = 0; qs < 4; ++qs) {
        const u16* qp = Qg + ((size_t)bh * 2048 + q0 + qs * 16 + fr) * 64 + fg * 8;
        qf[qs][0] = ld8(qp);
        qf[qs][1] = ld8(qp + 32);
    }

    f32x4 o[4][4] = {};                 // o[dj][qs]: d=dj*16+fg*4+r, q=qs*16+fr
    float psum[4] = {0.f, 0.f, 0.f, 0.f};

    const int srow = lane >> 3;
    const int scb = (lane & 7) * 16;
    const float* mrow = masks + b * 2048;

    auto STAGE = [&](int buf, int kv0) {
        #pragma unroll
        for (int j = 0; j < 2; ++j) {
            const int r0 = wave * 16 + j * 8;
            const int row = r0 + srow;
            const int sw = scb ^ ((row & 7) << 4);
            ASYNC16((const char*)(Kg + ((size_t)bh * 2048 + kv0 + row) * 64) + sw,
                    smem + buf * 8192 + r0 * 128);
            ASYNC16((const char*)(Vt + ((size_t)bh * 64 + row) * 2048 + kv0) + sw,
                    smem + 16384 + buf * 8192 + r0 * 128);
        }
    };

    const int t0 = ((bidL >> 8) & 1) << 4;   // co-resident blocks start 16 tiles apart
    STAGE(0, t0 * 64);
    for (int it = 0; it < 32; it += 2) {
        #pragma unroll
        for (int half = 0; half < 2; ++half) {
            const int tile = (t0 + it + half) & 31;
            const int kv = tile * 64;
            const int kb = half * 8192;            // compile-time dbuf bases
            const int vb = 16384 + half * 8192;
            __syncthreads();                        // buf[half] staged
            if (it + half < 31) STAGE(half ^ 1, ((tile + 1) & 31) * 64);

            float4 mv[4];
            #pragma unroll
            for (int nj = 0; nj < 4; ++nj)
                mv[nj] = *(const float4*)(mrow + kv + nj * 16 + fg * 4);

            // per 32-key half: QK -> softmax -> in-reg transpose -> PV
            #pragma unroll
            for (int hh = 0; hh < 2; ++hh) {
                const int aK = hh ? a1 : a0;        // V frag byte-half for this hh
                f32x4 s[2][4];
                #pragma unroll
                for (int njl = 0; njl < 2; ++njl) {
                    const int nj = hh * 2 + njl;
                    bf16x8 k0 = ld8(smem + kb + nj * 2048 + a0);
                    bf16x8 k1 = ld8(smem + kb + nj * 2048 + a1);
                    __builtin_amdgcn_s_setprio(1);
                    #pragma unroll
                    for (int qs = 0; qs < 4; ++qs) {
                        f32x4 z = {0.f, 0.f, 0.f, 0.f};
                        z = __builtin_amdgcn_mfma_f32_16x16x32_bf16(k0, qf[qs][0], z, 0, 0, 0);
                        s[njl][qs] = __builtin_amdgcn_mfma_f32_16x16x32_bf16(k1, qf[qs][1], z, 0, 0, 0);
                    }
                    __builtin_amdgcn_s_setprio(0);
                }
                // softmax in place (p overwrites s) + partial denominator
                #pragma unroll
                for (int njl = 0; njl < 2; ++njl) {
                    const int nj = hh * 2 + njl;
                    #pragma unroll
                    for (int qs = 0; qs < 4; ++qs)
                        #pragma unroll
                        for (int r = 0; r < 4; ++r) {
                            const float p = __builtin_exp2f(s[njl][qs][r]) * mv[nj][r];
                            psum[qs] += p;
                            s[njl][qs][r] = p;
                        }
                }
                // pack + 4x4 cross-lane transpose -> PV B-operand fragments
                bf16x8 pa[4];
                #pragma unroll
                for (int qs = 0; qs < 4; ++qs) {
                    u32 m0, m1, m2, m3;   // word (W1=njl, W0=r-pair)
                    asm("v_cvt_pk_bf16_f32 %0, %1, %2" : "=v"(m0) : "v"(s[0][qs][0]), "v"(s[0][qs][1]));
                    asm("v_cvt_pk_bf16_f32 %0, %1, %2" : "=v"(m1) : "v"(s[0][qs][2]), "v"(s[0][qs][3]));
                    asm("v_cvt_pk_bf16_f32 %0, %1, %2" : "=v"(m2) : "v"(s[1][qs][0]), "v"(s[1][qs][1]));
                    asm("v_cvt_pk_bf16_f32 %0, %1, %2" : "=v"(m3) : "v"(s[1][qs][2]), "v"(s[1][qs][3]));
                    // step 1: swap(L5, W1) on pairs differing only in W1
                    asm("v_permlane32_swap_b32 %0, %1" : "+v"(m0), "+v"(m2));
                    asm("v_permlane32_swap_b32 %0, %1" : "+v"(m1), "+v"(m3));
                    // step 2: swap(L4, W1)
                    asm("v_permlane16_swap_b32 %0, %1" : "+v"(m0), "+v"(m2));
                    asm("v_permlane16_swap_b32 %0, %1" : "+v"(m1), "+v"(m3));
                    pa[qs] = __builtin_bit_cast(bf16x8, u32x4{m0, m1, m2, m3});
                }

                // PV: o[dj][qs] += mfma(V^T frag, P frag)
                __builtin_amdgcn_s_setprio(1);
                #pragma unroll
                for (int dj = 0; dj < 4; ++dj) {
                    bf16x8 v = ld8(smem + vb + dj * 2048 + aK);
                    #pragma unroll
                    for (int qs = 0; qs < 4; ++qs)
                        o[dj][qs] = __builtin_amdgcn_mfma_f32_16x16x32_bf16(v, pa[qs], o[dj][qs], 0, 0, 0);
                }
                __builtin_amdgcn_s_setprio(0);
            }
        }
    }

    // deferred denominator: reduce over fg groups (lane bits 4,5)
    #pragma unroll
    for (int qs = 0; qs < 4; ++qs) {
        float s = psum[qs];
        s += __shfl_xor(s, 16, 64);
        s += __shfl_xor(s, 32, 64);
        const float inv = 1.0f / s;
        const int q = q0 + qs * 16 + fr;
        u16* dst = X2 + ((size_t)(b * 2048 + q)) * 1024 + h * 64 + fg * 4;
        #pragma unroll
        for (int dj = 0; dj < 4; ++dj) {
            u16x4 st;
            #pragma unroll
            for (int r = 0; r < 4; ++r) st[r] = f2bf(o[dj][qs][r] * inv);
            *(u16x4*)(dst + dj * 16) = st;
        }
    }
}

// ---------------- launch ----------------
extern "C" void kernel_launch(void* const* d_in, const int* in_sizes, int n_in,
                              void* d_out, int out_size, void* d_ws, size_t ws_size,
                              hipStream_t stream) {
    const float* query = (const float*)d_in[0];
    const float* masks = (const float*)d_in[1];
    const float* Wq = (const float*)d_in[2];
    const float* bq = (const float*)d_in[3];
    const float* Wk = (const float*)d_in[4];
    const float* bk = (const float*)d_in[5];
    const float* Wv = (const float*)d_in[6];
    const float* bv = (const float*)d_in[7];
    const float* Wo = (const float*)d_in[8];
    const float* bo = (const float*)d_in[9];
    float* out = (float*)d_out;

    // workspace (72 MB):
    //  [ 0,16M): Xb (bf16 query)  -> reused as X2 (attn out) after QKV GEMM
    //  [16,22M): Wcat  [22,24M): Wob
    //  [24,40M): Qg   [40,56M): Kg   [56,72M): Vt (written transposed by GEMM)
    char* ws = (char*)d_ws;
    u16* Xb   = (u16*)(ws);
    u16* Wcat = (u16*)(ws + (16u << 20));
    u16* Wob  = (u16*)(ws + (22u << 20));
    u16* Qg   = (u16*)(ws + (24u << 20));
    u16* Kg   = (u16*)(ws + (40u << 20));
    u16* Vt   = (u16*)(ws + (56u << 20));
    u16* X2   = Xb;   // Xb dead after QKV GEMM

    cvt_f32_bf16<<<8192, 256, 0, stream>>>(query, Xb, 8192 * 1024 / 4);
    cvt_f32_bf16<<<1024, 256, 0, stream>>>(Wq, Wcat,               1024 * 1024 / 4);
    cvt_f32_bf16<<<1024, 256, 0, stream>>>(Wk, Wcat + 1024 * 1024, 1024 * 1024 / 4);
    cvt_f32_bf16<<<1024, 256, 0, stream>>>(Wv, Wcat + 2 * 1024 * 1024, 1024 * 1024 / 4);
    cvt_f32_bf16<<<1024, 256, 0, stream>>>(Wo, Wob, 1024 * 1024 / 4);

    gemm_bt<0><<<dim3(24, 64), 256, 0, stream>>>(Xb, Wcat, bq, bk, bv, Qg, Kg, Vt, nullptr);
    attn_fwd<<<512, 256, 0, stream>>>(Qg, Kg, Vt, masks, X2);
    gemm_bt<1><<<dim3(8, 64), 256, 0, stream>>>(X2, Wob, bo, nullptr, nullptr, nullptr,
                                                nullptr, nullptr, out);
}

// Round 9
// 224.782 us; speedup vs baseline: 1.1251x; 1.0079x over previous
//
#include <hip/hip_runtime.h>

typedef unsigned short u16;
typedef unsigned int u32;
typedef u16 u16x4 __attribute__((ext_vector_type(4)));
typedef u16 u16x8 __attribute__((ext_vector_type(8)));
typedef u32 u32x4 __attribute__((ext_vector_type(4)));
typedef __bf16 bf16x8 __attribute__((ext_vector_type(8)));
typedef float f32x4 __attribute__((ext_vector_type(4)));

#define GPTR(p) (const __attribute__((address_space(1))) void*)(p)
#define LPTR(p) (__attribute__((address_space(3))) void*)(p)
// async global->LDS, 16B per lane; LDS dest = wave-uniform base + lane*16
#define ASYNC16(g, l) __builtin_amdgcn_global_load_lds(GPTR(g), LPTR(l), 16, 0, 0)

// fp32 -> bf16 RTNE (epilogue / non-hot paths)
__device__ __forceinline__ u16 f2bf(float f) {
    u32 u = __builtin_bit_cast(u32, f);
    return (u16)((u + 0x7fffu + ((u >> 16) & 1u)) >> 16);
}
__device__ __forceinline__ bf16x8 ld8(const void* p) {
    return __builtin_bit_cast(bf16x8, *(const u16x8*)p);
}

// ---------------- fp32 -> bf16 conversion ----------------
__global__ void cvt_f32_bf16(const float* __restrict__ in, u16* __restrict__ out, int n4) {
    int i = blockIdx.x * blockDim.x + threadIdx.x;
    if (i >= n4) return;
    float4 v = ((const float4*)in)[i];
    ushort4 o;
    o.x = f2bf(v.x); o.y = f2bf(v.y); o.z = f2bf(v.z); o.w = f2bf(v.w);
    ((ushort4*)out)[i] = o;
}

// ---------------- GEMM: C[m][n] = sum_k A[m][k]*B[n][k]  (B^T input) ----------
// MODE 0: QKV fused (N=3072): out = (C + bias[n]) * (n<1024 ? QSCALE : 1).
//   Q,K -> [b][h][s][64] bf16;  V -> TRANSPOSED [b][h][64][s] bf16.
// MODE 1: out-proj (N=1024): OF[m][n] = C + b0[n]  (fp32)
template<int MODE>
__global__ __launch_bounds__(256, 2) void gemm_bt(
    const u16* __restrict__ A, const u16* __restrict__ B,
    const float* __restrict__ b0, const float* __restrict__ b1, const float* __restrict__ b2,
    u16* __restrict__ O0, u16* __restrict__ O1, u16* __restrict__ O2,
    float* __restrict__ OF)
{
    constexpr int K = 1024;
    __shared__ __align__(16) u16 As[128 * 32];
    __shared__ __align__(16) u16 Bs[128 * 32];
    const int tid = threadIdx.x;
    const int wave = tid >> 6, lane = tid & 63;
    const int m0 = blockIdx.y * 128, n0 = blockIdx.x * 128;
    const int wm = (wave >> 1) * 64, wn = (wave & 1) * 64;
    const int fr = lane & 15, fg = lane >> 4;

    f32x4 acc[4][4] = {};

    const int srow = lane >> 2;
    const int scol = (lane & 3) * 8;
    const u16* aSrc = A + (size_t)(m0 + wave * 32 + srow) * K + scol;
    const u16* bSrc = B + (size_t)(n0 + wave * 32 + srow) * K + scol;
    u16* const aDst0 = &As[(wave * 32) * 32];
    u16* const aDst1 = &As[(wave * 32 + 16) * 32];
    u16* const bDst0 = &Bs[(wave * 32) * 32];
    u16* const bDst1 = &Bs[(wave * 32 + 16) * 32];

    for (int kt = 0; kt < K; kt += 32) {
        ASYNC16(aSrc + kt,          aDst0);
        ASYNC16(aSrc + kt + 16 * K, aDst1);
        ASYNC16(bSrc + kt,          bDst0);
        ASYNC16(bSrc + kt + 16 * K, bDst1);
        __syncthreads();
        bf16x8 af[4], bfv[4];
        #pragma unroll
        for (int i = 0; i < 4; ++i) af[i]  = ld8(&As[(wm + i * 16 + fr) * 32 + fg * 8]);
        #pragma unroll
        for (int j = 0; j < 4; ++j) bfv[j] = ld8(&Bs[(wn + j * 16 + fr) * 32 + fg * 8]);
        #pragma unroll
        for (int i = 0; i < 4; ++i)
            #pragma unroll
            for (int j = 0; j < 4; ++j)
                acc[i][j] = __builtin_amdgcn_mfma_f32_16x16x32_bf16(af[i], bfv[j], acc[i][j], 0, 0, 0);
        __syncthreads();
    }

    if constexpr (MODE == 0) {
        const float QSCALE = 0.125f * 1.44269504f;   // 1/sqrt(64) * log2(e)
        #pragma unroll
        for (int j = 0; j < 4; ++j) {
            const int n = n0 + wn + j * 16 + fr;
            const int sel = n >> 10;          // 0=Q 1=K 2=V (uniform per fragment)
            const int w = n & 1023;
            const float bb = (sel == 0 ? b0 : sel == 1 ? b1 : b2)[w];
            const int h = w >> 6, d = w & 63;
            if (sel == 2) {
                // V transposed: Vt[(bi*16+h)*64 + d][s], s-consecutive -> u16x4
                #pragma unroll
                for (int i = 0; i < 4; ++i) {
                    const int m = m0 + wm + i * 16 + fg * 4;   // s base (4-aligned)
                    u16x4 st;
                    #pragma unroll
                    for (int r = 0; r < 4; ++r) st[r] = f2bf(acc[i][j][r] + bb);
                    *(u16x4*)&O2[((size_t)(((m >> 11) * 16 + h) * 64 + d)) * 2048 + (m & 2047)] = st;
                }
            } else {
                const float scale = (sel == 0) ? QSCALE : 1.0f;
                u16* const dst = (sel == 0 ? O0 : O1);
                #pragma unroll
                for (int i = 0; i < 4; ++i) {
                    #pragma unroll
                    for (int r = 0; r < 4; ++r) {
                        const int m = m0 + wm + i * 16 + fg * 4 + r;
                        dst[(((size_t)((m >> 11) * 16 + h) * 2048 + (m & 2047)) << 6) + d] =
                            f2bf((acc[i][j][r] + bb) * scale);
                    }
                }
            }
        }
    } else {
        #pragma unroll
        for (int j = 0; j < 4; ++j) {
            const int n = n0 + wn + j * 16 + fr;
            const float bb = b0[n];
            #pragma unroll
            for (int i = 0; i < 4; ++i) {
                #pragma unroll
                for (int r = 0; r < 4; ++r) {
                    const int m = m0 + wm + i * 16 + fg * 4 + r;
                    OF[(size_t)m * 1024 + n] = acc[i][j][r] + bb;
                }
            }
        }
    }
}

// ---------------- flash attention: in-reg P, QROWS=32, 16 waves/CU ------------
// Q [bh][s][64] pre-scaled by 0.125*log2e, K [bh][s][64], Vt [bh][64][s],
// masks [b][s] fp32 (binary), out X2 [b][s][h*64+d] bf16.
// 4 waves x 32 q-rows; grid 1024 = 4 blocks/CU (LDS 32KB, VGPR<=128) ->
// 16 waves/CU = 4/SIMD to fill the QK->softmax->pack->PV dependency bubbles
// (R8 evidence: wall 4.6k cyc/wave-tile vs ~1k cyc work at 2 waves/SIMD).
// Swapped QK: P = mfma(K,Q) -> lane(fr,fg) holds P[key=nj*16+fg*4+r][q=fr].
// In-register 4x4 cross-lane transpose to PV B-operand:
//   v_permlane32_swap_b32 == swap(L5, word), v_permlane16_swap_b32 == swap(L4, word)
// No-max softmax, deferred denominator, mask folded multiplicatively.
// smem 32KB: K dbuf [0,16K), V dbuf [16K,32K).
__global__ __launch_bounds__(256, 4) void attn_fwd(
    const u16* __restrict__ Qg, const u16* __restrict__ Kg, const u16* __restrict__ Vt,
    const float* __restrict__ masks, u16* __restrict__ X2)
{
    __shared__ __align__(16) char smem[32768];
    const int tid = threadIdx.x;
    const int wave = tid >> 6, lane = tid & 63;

    // bijective XCD swizzle: 1024 wgs / 8 XCDs -> 128 contiguous wgs (8 bh) per XCD
    const int bidL = blockIdx.x;
    const int wg = ((bidL & 7) << 7) | (bidL >> 3);
    const int bh = wg >> 4;                        // 16 q-blocks per bh
    const int q0 = (wg & 15) * 128 + wave * 32;
    const int b = bh >> 4, h = bh & 15;
    const int fr = lane & 15, fg = lane >> 4;
    const int swz = (fr & 7) << 4;

    // loop-invariant LDS byte addresses
    const int a0 = fr * 128 + ((fg * 16) ^ swz);          // frag low 64B (k/d 0-31)
    const int a1 = fr * 128 + ((64 + fg * 16) ^ swz);     // frag high 64B

    // Q fragments (B-operand): 2 strips of 16 rows
    bf16x8 qf[2][2];
    #pragma unroll
    for (int qs = 0; qs < 2; ++qs) {
        const u16* qp = Qg + ((size_t)bh * 2048 + q0 + qs * 16 + fr) * 64 + fg * 8;
        qf[qs][0] = ld8(qp);
        qf[qs][1] = ld8(qp + 32);
    }

    f32x4 o[4][2] = {};                 // o[dj][qs]: d=dj*16+fg*4+r, q=qs*16+fr
    float psum[2] = {0.f, 0.f};

    const int srow = lane >> 3;
    const int scb = (lane & 7) * 16;
    const float* mrow = masks + b * 2048;

    auto STAGE = [&](int buf, int kv0) {
        #pragma unroll
        for (int j = 0; j < 2; ++j) {
            const int r0 = wave * 16 + j * 8;
            const int row = r0 + srow;
            const int sw = scb ^ ((row & 7) << 4);
            ASYNC16((const char*)(Kg + ((size_t)bh * 2048 + kv0 + row) * 64) + sw,
                    smem + buf * 8192 + r0 * 128);
            ASYNC16((const char*)(Vt + ((size_t)bh * 64 + row) * 2048 + kv0) + sw,
                    smem + 16384 + buf * 8192 + r0 * 128);
        }
    };

    // co-resident blocks start 8 tiles apart (key order commutes: no-max
    // softmax + deferred denominator) -> pipe bursts interleave across blocks
    const int t0 = (((bidL >> 8) & 3) << 3);
    STAGE(0, t0 * 64);
    for (int it = 0; it < 32; it += 2) {
        #pragma unroll
        for (int half = 0; half < 2; ++half) {
            const int tile = (t0 + it + half) & 31;
            const int kv = tile * 64;
            const int kb = half * 8192;            // compile-time dbuf bases
            const int vb = 16384 + half * 8192;
            __syncthreads();                        // buf[half] staged
            if (it + half < 31) STAGE(half ^ 1, ((tile + 1) & 31) * 64);

            float4 mv[4];
            #pragma unroll
            for (int nj = 0; nj < 4; ++nj)
                mv[nj] = *(const float4*)(mrow + kv + nj * 16 + fg * 4);

            // per 32-key half: QK -> softmax -> in-reg transpose -> PV
            #pragma unroll
            for (int hh = 0; hh < 2; ++hh) {
                const int aK = hh ? a1 : a0;        // V frag byte-half for this hh
                f32x4 s[2][2];
                #pragma unroll
                for (int njl = 0; njl < 2; ++njl) {
                    const int nj = hh * 2 + njl;
                    bf16x8 k0 = ld8(smem + kb + nj * 2048 + a0);
                    bf16x8 k1 = ld8(smem + kb + nj * 2048 + a1);
                    __builtin_amdgcn_s_setprio(1);
                    #pragma unroll
                    for (int qs = 0; qs < 2; ++qs) {
                        f32x4 z = {0.f, 0.f, 0.f, 0.f};
                        z = __builtin_amdgcn_mfma_f32_16x16x32_bf16(k0, qf[qs][0], z, 0, 0, 0);
                        s[njl][qs] = __builtin_amdgcn_mfma_f32_16x16x32_bf16(k1, qf[qs][1], z, 0, 0, 0);
                    }
                    __builtin_amdgcn_s_setprio(0);
                }
                // softmax in place + partial denominator
                #pragma unroll
                for (int njl = 0; njl < 2; ++njl) {
                    const int nj = hh * 2 + njl;
                    #pragma unroll
                    for (int qs = 0; qs < 2; ++qs)
                        #pragma unroll
                        for (int r = 0; r < 4; ++r) {
                            const float p = __builtin_exp2f(s[njl][qs][r]) * mv[nj][r];
                            psum[qs] += p;
                            s[njl][qs][r] = p;
                        }
                }
                // pack + 4x4 cross-lane transpose -> PV B-operand fragments
                bf16x8 pa[2];
                #pragma unroll
                for (int qs = 0; qs < 2; ++qs) {
                    u32 m0, m1, m2, m3;   // word (W1=njl, W0=r-pair)
                    asm("v_cvt_pk_bf16_f32 %0, %1, %2" : "=v"(m0) : "v"(s[0][qs][0]), "v"(s[0][qs][1]));
                    asm("v_cvt_pk_bf16_f32 %0, %1, %2" : "=v"(m1) : "v"(s[0][qs][2]), "v"(s[0][qs][3]));
                    asm("v_cvt_pk_bf16_f32 %0, %1, %2" : "=v"(m2) : "v"(s[1][qs][0]), "v"(s[1][qs][1]));
                    asm("v_cvt_pk_bf16_f32 %0, %1, %2" : "=v"(m3) : "v"(s[1][qs][2]), "v"(s[1][qs][3]));
                    // step 1: swap(L5, W1); step 2: swap(L4, W1)
                    asm("v_permlane32_swap_b32 %0, %1" : "+v"(m0), "+v"(m2));
                    asm("v_permlane32_swap_b32 %0, %1" : "+v"(m1), "+v"(m3));
                    asm("v_permlane16_swap_b32 %0, %1" : "+v"(m0), "+v"(m2));
                    asm("v_permlane16_swap_b32 %0, %1" : "+v"(m1), "+v"(m3));
                    pa[qs] = __builtin_bit_cast(bf16x8, u32x4{m0, m1, m2, m3});
                }

                // PV: o[dj][qs] += mfma(V^T frag, P frag)
                __builtin_amdgcn_s_setprio(1);
                #pragma unroll
                for (int dj = 0; dj < 4; ++dj) {
                    bf16x8 v = ld8(smem + vb + dj * 2048 + aK);
                    #pragma unroll
                    for (int qs = 0; qs < 2; ++qs)
                        o[dj][qs] = __builtin_amdgcn_mfma_f32_16x16x32_bf16(v, pa[qs], o[dj][qs], 0, 0, 0);
                }
                __builtin_amdgcn_s_setprio(0);
            }
        }
    }

    // deferred denominator: reduce over fg groups (lane bits 4,5)
    #pragma unroll
    for (int qs = 0; qs < 2; ++qs) {
        float s = psum[qs];
        s += __shfl_xor(s, 16, 64);
        s += __shfl_xor(s, 32, 64);
        const float inv = 1.0f / s;
        const int q = q0 + qs * 16 + fr;
        u16* dst = X2 + ((size_t)(b * 2048 + q)) * 1024 + h * 64 + fg * 4;
        #pragma unroll
        for (int dj = 0; dj < 4; ++dj) {
            u16x4 st;
            #pragma unroll
            for (int r = 0; r < 4; ++r) st[r] = f2bf(o[dj][qs][r] * inv);
            *(u16x4*)(dst + dj * 16) = st;
        }
    }
}

// ---------------- launch ----------------
extern "C" void kernel_launch(void* const* d_in, const int* in_sizes, int n_in,
                              void* d_out, int out_size, void* d_ws, size_t ws_size,
                              hipStream_t stream) {
    const float* query = (const float*)d_in[0];
    const float* masks = (const float*)d_in[1];
    const float* Wq = (const float*)d_in[2];
    const float* bq = (const float*)d_in[3];
    const float* Wk = (const float*)d_in[4];
    const float* bk = (const float*)d_in[5];
    const float* Wv = (const float*)d_in[6];
    const float* bv = (const float*)d_in[7];
    const float* Wo = (const float*)d_in[8];
    const float* bo = (const float*)d_in[9];
    float* out = (float*)d_out;

    // workspace (72 MB):
    //  [ 0,16M): Xb (bf16 query)  -> reused as X2 (attn out) after QKV GEMM
    //  [16,22M): Wcat  [22,24M): Wob
    //  [24,40M): Qg   [40,56M): Kg   [56,72M): Vt (written transposed by GEMM)
    char* ws = (char*)d_ws;
    u16* Xb   = (u16*)(ws);
    u16* Wcat = (u16*)(ws + (16u << 20));
    u16* Wob  = (u16*)(ws + (22u << 20));
    u16* Qg   = (u16*)(ws + (24u << 20));
    u16* Kg   = (u16*)(ws + (40u << 20));
    u16* Vt   = (u16*)(ws + (56u << 20));
    u16* X2   = Xb;   // Xb dead after QKV GEMM

    cvt_f32_bf16<<<8192, 256, 0, stream>>>(query, Xb, 8192 * 1024 / 4);
    cvt_f32_bf16<<<1024, 256, 0, stream>>>(Wq, Wcat,               1024 * 1024 / 4);
    cvt_f32_bf16<<<1024, 256, 0, stream>>>(Wk, Wcat + 1024 * 1024, 1024 * 1024 / 4);
    cvt_f32_bf16<<<1024, 256, 0, stream>>>(Wv, Wcat + 2 * 1024 * 1024, 1024 * 1024 / 4);
    cvt_f32_bf16<<<1024, 256, 0, stream>>>(Wo, Wob, 1024 * 1024 / 4);

    gemm_bt<0><<<dim3(24, 64), 256, 0, stream>>>(Xb, Wcat, bq, bk, bv, Qg, Kg, Vt, nullptr);
    attn_fwd<<<1024, 256, 0, stream>>>(Qg, Kg, Vt, masks, X2);
    gemm_bt<1><<<dim3(8, 64), 256, 0, stream>>>(X2, Wob, bo, nullptr, nullptr, nullptr,
                                                nullptr, nullptr, out);
}

// Round 10
// 196.579 us; speedup vs baseline: 1.2865x; 1.1435x over previous
//
#include <hip/hip_runtime.h>

typedef unsigned short u16;
typedef unsigned int u32;
typedef u16 u16x4 __attribute__((ext_vector_type(4)));
typedef u16 u16x8 __attribute__((ext_vector_type(8)));
typedef u32 u32x4 __attribute__((ext_vector_type(4)));
typedef __bf16 bf16x8 __attribute__((ext_vector_type(8)));
typedef float f32x4 __attribute__((ext_vector_type(4)));

#define GPTR(p) (const __attribute__((address_space(1))) void*)(p)
#define LPTR(p) (__attribute__((address_space(3))) void*)(p)
// async global->LDS, 16B per lane; LDS dest = wave-uniform base + lane*16
#define ASYNC16(g, l) __builtin_amdgcn_global_load_lds(GPTR(g), LPTR(l), 16, 0, 0)

// raw v_exp_f32 (no denormal-range fixup; inputs here are |x| < 40)
#if __has_builtin(__builtin_amdgcn_exp2f)
#define EXP2(x) __builtin_amdgcn_exp2f(x)
#else
#define EXP2(x) __builtin_exp2f(x)
#endif

// fp32 -> bf16 RTNE (epilogue / non-hot paths)
__device__ __forceinline__ u16 f2bf(float f) {
    u32 u = __builtin_bit_cast(u32, f);
    return (u16)((u + 0x7fffu + ((u >> 16) & 1u)) >> 16);
}
__device__ __forceinline__ bf16x8 ld8(const void* p) {
    return __builtin_bit_cast(bf16x8, *(const u16x8*)p);
}

// ---------------- fp32 -> bf16 conversion ----------------
__global__ void cvt_f32_bf16(const float* __restrict__ in, u16* __restrict__ out, int n4) {
    int i = blockIdx.x * blockDim.x + threadIdx.x;
    if (i >= n4) return;
    float4 v = ((const float4*)in)[i];
    ushort4 o;
    o.x = f2bf(v.x); o.y = f2bf(v.y); o.z = f2bf(v.z); o.w = f2bf(v.w);
    ((ushort4*)out)[i] = o;
}

// ---------------- GEMM: C[m][n] = sum_k A[m][k]*B[n][k]  (B^T input) ----------
// MODE 0: QKV fused (N=3072): out = (C + bias[n]) * (n<1024 ? QSCALE : 1).
//   Q,K -> [b][h][s][64] bf16;  V -> TRANSPOSED [b][h][64][s] bf16.
// MODE 1: out-proj (N=1024): OF[m][n] = C + b0[n]  (fp32)
template<int MODE>
__global__ __launch_bounds__(256, 2) void gemm_bt(
    const u16* __restrict__ A, const u16* __restrict__ B,
    const float* __restrict__ b0, const float* __restrict__ b1, const float* __restrict__ b2,
    u16* __restrict__ O0, u16* __restrict__ O1, u16* __restrict__ O2,
    float* __restrict__ OF)
{
    constexpr int K = 1024;
    __shared__ __align__(16) u16 As[128 * 32];
    __shared__ __align__(16) u16 Bs[128 * 32];
    const int tid = threadIdx.x;
    const int wave = tid >> 6, lane = tid & 63;
    const int m0 = blockIdx.y * 128, n0 = blockIdx.x * 128;
    const int wm = (wave >> 1) * 64, wn = (wave & 1) * 64;
    const int fr = lane & 15, fg = lane >> 4;

    f32x4 acc[4][4] = {};

    const int srow = lane >> 2;
    const int scol = (lane & 3) * 8;
    const u16* aSrc = A + (size_t)(m0 + wave * 32 + srow) * K + scol;
    const u16* bSrc = B + (size_t)(n0 + wave * 32 + srow) * K + scol;
    u16* const aDst0 = &As[(wave * 32) * 32];
    u16* const aDst1 = &As[(wave * 32 + 16) * 32];
    u16* const bDst0 = &Bs[(wave * 32) * 32];
    u16* const bDst1 = &Bs[(wave * 32 + 16) * 32];

    for (int kt = 0; kt < K; kt += 32) {
        ASYNC16(aSrc + kt,          aDst0);
        ASYNC16(aSrc + kt + 16 * K, aDst1);
        ASYNC16(bSrc + kt,          bDst0);
        ASYNC16(bSrc + kt + 16 * K, bDst1);
        __syncthreads();
        bf16x8 af[4], bfv[4];
        #pragma unroll
        for (int i = 0; i < 4; ++i) af[i]  = ld8(&As[(wm + i * 16 + fr) * 32 + fg * 8]);
        #pragma unroll
        for (int j = 0; j < 4; ++j) bfv[j] = ld8(&Bs[(wn + j * 16 + fr) * 32 + fg * 8]);
        #pragma unroll
        for (int i = 0; i < 4; ++i)
            #pragma unroll
            for (int j = 0; j < 4; ++j)
                acc[i][j] = __builtin_amdgcn_mfma_f32_16x16x32_bf16(af[i], bfv[j], acc[i][j], 0, 0, 0);
        __syncthreads();
    }

    if constexpr (MODE == 0) {
        const float QSCALE = 0.125f * 1.44269504f;   // 1/sqrt(64) * log2(e)
        #pragma unroll
        for (int j = 0; j < 4; ++j) {
            const int n = n0 + wn + j * 16 + fr;
            const int sel = n >> 10;          // 0=Q 1=K 2=V (uniform per fragment)
            const int w = n & 1023;
            const float bb = (sel == 0 ? b0 : sel == 1 ? b1 : b2)[w];
            const int h = w >> 6, d = w & 63;
            if (sel == 2) {
                // V transposed: Vt[(bi*16+h)*64 + d][s], s-consecutive -> u16x4
                #pragma unroll
                for (int i = 0; i < 4; ++i) {
                    const int m = m0 + wm + i * 16 + fg * 4;   // s base (4-aligned)
                    u16x4 st;
                    #pragma unroll
                    for (int r = 0; r < 4; ++r) st[r] = f2bf(acc[i][j][r] + bb);
                    *(u16x4*)&O2[((size_t)(((m >> 11) * 16 + h) * 64 + d)) * 2048 + (m & 2047)] = st;
                }
            } else {
                const float scale = (sel == 0) ? QSCALE : 1.0f;
                u16* const dst = (sel == 0 ? O0 : O1);
                #pragma unroll
                for (int i = 0; i < 4; ++i) {
                    #pragma unroll
                    for (int r = 0; r < 4; ++r) {
                        const int m = m0 + wm + i * 16 + fg * 4 + r;
                        dst[(((size_t)((m >> 11) * 16 + h) * 2048 + (m & 2047)) << 6) + d] =
                            f2bf((acc[i][j][r] + bb) * scale);
                    }
                }
            }
        }
    } else {
        #pragma unroll
        for (int j = 0; j < 4; ++j) {
            const int n = n0 + wn + j * 16 + fr;
            const float bb = b0[n];
            #pragma unroll
            for (int i = 0; i < 4; ++i) {
                #pragma unroll
                for (int r = 0; r < 4; ++r) {
                    const int m = m0 + wm + i * 16 + fg * 4 + r;
                    OF[(size_t)m * 1024 + n] = acc[i][j][r] + bb;
                }
            }
        }
    }
}

// ---------------- flash attention: in-reg P, VALU-lean softmax ---------------
// Q [bh][s][64] pre-scaled by 0.125*log2e, K [bh][s][64], Vt [bh][64][s],
// masks [b][s] fp32 (binary), out X2 [b][s][h*64+d] bf16.
// 4 waves x 32 q-rows; grid 1024 = 4 blocks/CU; smem 32KB (K/V dbuf).
// VALU cuts vs R9 (kernel was VALU-bound at 67% busy):
//  - EXP2 = raw v_exp_f32 (no denormal fixup sequence)
//  - denominator via MFMA row-sum with ONES A-operand (kills psum adds +
//    end shuffles; every lane gets den in den[qs][*])
//  - shared FZ zero C-operand for QK (kills per-tile v_mov zero bursts)
// Swapped QK: P = mfma(K,Q) -> lane(fr,fg) holds P[key=nj*16+fg*4+r][q=fr].
// In-register 4x4 cross-lane transpose to PV B-operand via
// v_permlane32_swap_b32 (swap L5<->word) + v_permlane16_swap_b32 (swap L4<->word).
__global__ __launch_bounds__(256, 4) void attn_fwd(
    const u16* __restrict__ Qg, const u16* __restrict__ Kg, const u16* __restrict__ Vt,
    const float* __restrict__ masks, u16* __restrict__ X2)
{
    __shared__ __align__(16) char smem[32768];
    const int tid = threadIdx.x;
    const int wave = tid >> 6, lane = tid & 63;

    // bijective XCD swizzle: 1024 wgs / 8 XCDs -> 128 contiguous wgs (8 bh) per XCD
    const int bidL = blockIdx.x;
    const int wg = ((bidL & 7) << 7) | (bidL >> 3);
    const int bh = wg >> 4;                        // 16 q-blocks per bh
    const int q0 = (wg & 15) * 128 + wave * 32;
    const int b = bh >> 4, h = bh & 15;
    const int fr = lane & 15, fg = lane >> 4;
    const int swz = (fr & 7) << 4;

    // loop-invariant LDS byte addresses
    const int a0 = fr * 128 + ((fg * 16) ^ swz);          // frag low 64B (k/d 0-31)
    const int a1 = fr * 128 + ((64 + fg * 16) ^ swz);     // frag high 64B

    // Q fragments (B-operand): 2 strips of 16 rows
    bf16x8 qf[2][2];
    #pragma unroll
    for (int qs = 0; qs < 2; ++qs) {
        const u16* qp = Qg + ((size_t)bh * 2048 + q0 + qs * 16 + fr) * 64 + fg * 8;
        qf[qs][0] = ld8(qp);
        qf[qs][1] = ld8(qp + 32);
    }

    f32x4 o[4][2] = {};                 // o[dj][qs]: d=dj*16+fg*4+r, q=qs*16+fr
    f32x4 den[2] = {};                  // softmax denominator (all 4 rows identical)
    const f32x4 FZ = {0.f, 0.f, 0.f, 0.f};                 // shared zero C-operand
    const u16x8 ONE_BITS = {0x3F80,0x3F80,0x3F80,0x3F80,0x3F80,0x3F80,0x3F80,0x3F80};
    const bf16x8 ONES = __builtin_bit_cast(bf16x8, ONE_BITS); // bf16 1.0 x8

    const int srow = lane >> 3;
    const int scb = (lane & 7) * 16;
    const float* mrow = masks + b * 2048;

    auto STAGE = [&](int buf, int kv0) {
        #pragma unroll
        for (int j = 0; j < 2; ++j) {
            const int r0 = wave * 16 + j * 8;
            const int row = r0 + srow;
            const int sw = scb ^ ((row & 7) << 4);
            ASYNC16((const char*)(Kg + ((size_t)bh * 2048 + kv0 + row) * 64) + sw,
                    smem + buf * 8192 + r0 * 128);
            ASYNC16((const char*)(Vt + ((size_t)bh * 64 + row) * 2048 + kv0) + sw,
                    smem + 16384 + buf * 8192 + r0 * 128);
        }
    };

    // co-resident blocks start 8 tiles apart (key order commutes: no-max
    // softmax + linear denominator) -> pipe bursts interleave across blocks
    const int t0 = (((bidL >> 8) & 3) << 3);
    STAGE(0, t0 * 64);
    for (int it = 0; it < 32; it += 2) {
        #pragma unroll
        for (int half = 0; half < 2; ++half) {
            const int tile = (t0 + it + half) & 31;
            const int kv = tile * 64;
            const int kb = half * 8192;            // compile-time dbuf bases
            const int vb = 16384 + half * 8192;
            __syncthreads();                        // buf[half] staged
            if (it + half < 31) STAGE(half ^ 1, ((tile + 1) & 31) * 64);

            float4 mv[4];
            #pragma unroll
            for (int nj = 0; nj < 4; ++nj)
                mv[nj] = *(const float4*)(mrow + kv + nj * 16 + fg * 4);

            // per 32-key half: QK -> softmax -> in-reg transpose -> PV
            #pragma unroll
            for (int hh = 0; hh < 2; ++hh) {
                const int aK = hh ? a1 : a0;        // V frag byte-half for this hh
                f32x4 s[2][2];
                #pragma unroll
                for (int njl = 0; njl < 2; ++njl) {
                    const int nj = hh * 2 + njl;
                    bf16x8 k0 = ld8(smem + kb + nj * 2048 + a0);
                    bf16x8 k1 = ld8(smem + kb + nj * 2048 + a1);
                    __builtin_amdgcn_s_setprio(1);
                    #pragma unroll
                    for (int qs = 0; qs < 2; ++qs) {
                        f32x4 z = __builtin_amdgcn_mfma_f32_16x16x32_bf16(k0, qf[qs][0], FZ, 0, 0, 0);
                        s[njl][qs] = __builtin_amdgcn_mfma_f32_16x16x32_bf16(k1, qf[qs][1], z, 0, 0, 0);
                    }
                    __builtin_amdgcn_s_setprio(0);
                }
                // softmax in place: p = exp2(s) * mask   (raw-rate v_exp_f32)
                #pragma unroll
                for (int njl = 0; njl < 2; ++njl) {
                    const int nj = hh * 2 + njl;
                    #pragma unroll
                    for (int qs = 0; qs < 2; ++qs)
                        #pragma unroll
                        for (int r = 0; r < 4; ++r)
                            s[njl][qs][r] = EXP2(s[njl][qs][r]) * mv[nj][r];
                }
                // pack + 4x4 cross-lane transpose -> PV B-operand fragments
                bf16x8 pa[2];
                #pragma unroll
                for (int qs = 0; qs < 2; ++qs) {
                    u32 m0, m1, m2, m3;   // word (W1=njl, W0=r-pair)
                    asm("v_cvt_pk_bf16_f32 %0, %1, %2" : "=v"(m0) : "v"(s[0][qs][0]), "v"(s[0][qs][1]));
                    asm("v_cvt_pk_bf16_f32 %0, %1, %2" : "=v"(m1) : "v"(s[0][qs][2]), "v"(s[0][qs][3]));
                    asm("v_cvt_pk_bf16_f32 %0, %1, %2" : "=v"(m2) : "v"(s[1][qs][0]), "v"(s[1][qs][1]));
                    asm("v_cvt_pk_bf16_f32 %0, %1, %2" : "=v"(m3) : "v"(s[1][qs][2]), "v"(s[1][qs][3]));
                    // step 1: swap(L5, W1); step 2: swap(L4, W1)
                    asm("v_permlane32_swap_b32 %0, %1" : "+v"(m0), "+v"(m2));
                    asm("v_permlane32_swap_b32 %0, %1" : "+v"(m1), "+v"(m3));
                    asm("v_permlane16_swap_b32 %0, %1" : "+v"(m0), "+v"(m2));
                    asm("v_permlane16_swap_b32 %0, %1" : "+v"(m1), "+v"(m3));
                    pa[qs] = __builtin_bit_cast(bf16x8, u32x4{m0, m1, m2, m3});
                }

                // PV + MFMA denominator (row-sum with ONES A-operand)
                __builtin_amdgcn_s_setprio(1);
                #pragma unroll
                for (int qs = 0; qs < 2; ++qs)
                    den[qs] = __builtin_amdgcn_mfma_f32_16x16x32_bf16(ONES, pa[qs], den[qs], 0, 0, 0);
                #pragma unroll
                for (int dj = 0; dj < 4; ++dj) {
                    bf16x8 v = ld8(smem + vb + dj * 2048 + aK);
                    #pragma unroll
                    for (int qs = 0; qs < 2; ++qs)
                        o[dj][qs] = __builtin_amdgcn_mfma_f32_16x16x32_bf16(v, pa[qs], o[dj][qs], 0, 0, 0);
                }
                __builtin_amdgcn_s_setprio(0);
            }
        }
    }

    // normalize + store (den available in every lane; no cross-lane reduce)
    #pragma unroll
    for (int qs = 0; qs < 2; ++qs) {
        const float inv = 1.0f / den[qs][0];
        const int q = q0 + qs * 16 + fr;
        u16* dst = X2 + ((size_t)(b * 2048 + q)) * 1024 + h * 64 + fg * 4;
        #pragma unroll
        for (int dj = 0; dj < 4; ++dj) {
            u16x4 st;
            #pragma unroll
            for (int r = 0; r < 4; ++r) st[r] = f2bf(o[dj][qs][r] * inv);
            *(u16x4*)(dst + dj * 16) = st;
        }
    }
}

// ---------------- launch ----------------
extern "C" void kernel_launch(void* const* d_in, const int* in_sizes, int n_in,
                              void* d_out, int out_size, void* d_ws, size_t ws_size,
                              hipStream_t stream) {
    const float* query = (const float*)d_in[0];
    const float* masks = (const float*)d_in[1];
    const float* Wq = (const float*)d_in[2];
    const float* bq = (const float*)d_in[3];
    const float* Wk = (const float*)d_in[4];
    const float* bk = (const float*)d_in[5];
    const float* Wv = (const float*)d_in[6];
    const float* bv = (const float*)d_in[7];
    const float* Wo = (const float*)d_in[8];
    const float* bo = (const float*)d_in[9];
    float* out = (float*)d_out;

    // workspace (72 MB):
    //  [ 0,16M): Xb (bf16 query)  -> reused as X2 (attn out) after QKV GEMM
    //  [16,22M): Wcat  [22,24M): Wob
    //  [24,40M): Qg   [40,56M): Kg   [56,72M): Vt (written transposed by GEMM)
    char* ws = (char*)d_ws;
    u16* Xb   = (u16*)(ws);
    u16* Wcat = (u16*)(ws + (16u << 20));
    u16* Wob  = (u16*)(ws + (22u << 20));
    u16* Qg   = (u16*)(ws + (24u << 20));
    u16* Kg   = (u16*)(ws + (40u << 20));
    u16* Vt   = (u16*)(ws + (56u << 20));
    u16* X2   = Xb;   // Xb dead after QKV GEMM

    cvt_f32_bf16<<<8192, 256, 0, stream>>>(query, Xb, 8192 * 1024 / 4);
    cvt_f32_bf16<<<1024, 256, 0, stream>>>(Wq, Wcat,               1024 * 1024 / 4);
    cvt_f32_bf16<<<1024, 256, 0, stream>>>(Wk, Wcat + 1024 * 1024, 1024 * 1024 / 4);
    cvt_f32_bf16<<<1024, 256, 0, stream>>>(Wv, Wcat + 2 * 1024 * 1024, 1024 * 1024 / 4);
    cvt_f32_bf16<<<1024, 256, 0, stream>>>(Wo, Wob, 1024 * 1024 / 4);

    gemm_bt<0><<<dim3(24, 64), 256, 0, stream>>>(Xb, Wcat, bq, bk, bv, Qg, Kg, Vt, nullptr);
    attn_fwd<<<1024, 256, 0, stream>>>(Qg, Kg, Vt, masks, X2);
    gemm_bt<1><<<dim3(8, 64), 256, 0, stream>>>(X2, Wob, bo, nullptr, nullptr, nullptr,
                                                nullptr, nullptr, out);
}

// Round 11
// 186.622 us; speedup vs baseline: 1.3552x; 1.0533x over previous
//
#include <hip/hip_runtime.h>

typedef unsigned short u16;
typedef unsigned int u32;
typedef u16 u16x4 __attribute__((ext_vector_type(4)));
typedef u16 u16x8 __attribute__((ext_vector_type(8)));
typedef u32 u32x4 __attribute__((ext_vector_type(4)));
typedef __bf16 bf16x8 __attribute__((ext_vector_type(8)));
typedef float f32x4 __attribute__((ext_vector_type(4)));

#define GPTR(p) (const __attribute__((address_space(1))) void*)(p)
#define LPTR(p) (__attribute__((address_space(3))) void*)(p)
// async global->LDS, 16B per lane; LDS dest = wave-uniform base + lane*16
#define ASYNC16(g, l) __builtin_amdgcn_global_load_lds(GPTR(g), LPTR(l), 16, 0, 0)

// raw v_exp_f32 (no denormal-range fixup; inputs here are |x| < 40)
#if __has_builtin(__builtin_amdgcn_exp2f)
#define EXP2(x) __builtin_amdgcn_exp2f(x)
#else
#define EXP2(x) __builtin_exp2f(x)
#endif

// fp32 -> bf16 RTNE (epilogue / non-hot paths)
__device__ __forceinline__ u16 f2bf(float f) {
    u32 u = __builtin_bit_cast(u32, f);
    return (u16)((u + 0x7fffu + ((u >> 16) & 1u)) >> 16);
}
__device__ __forceinline__ bf16x8 ld8(const void* p) {
    return __builtin_bit_cast(bf16x8, *(const u16x8*)p);
}

// ---------------- fused fp32 -> bf16 conversion (single dispatch) -------------
// blocks [0,8192): query -> Xb;  [8192,+1024) each: Wq,Wk,Wv -> Wcat, Wo -> Wob
__global__ void cvt_all(const float* __restrict__ q,
                        const float* __restrict__ wq, const float* __restrict__ wk,
                        const float* __restrict__ wv, const float* __restrict__ wo,
                        u16* __restrict__ xb, u16* __restrict__ wcat, u16* __restrict__ wob) {
    const int blk = blockIdx.x;
    const float* src;
    u16* dst;
    size_t base;
    if (blk < 8192) {
        src = q; dst = xb; base = (size_t)blk * 256;
    } else {
        const int t = blk - 8192;
        const int w = t >> 10;
        base = (size_t)(t & 1023) * 256;
        src = (w == 0) ? wq : (w == 1) ? wk : (w == 2) ? wv : wo;
        dst = (w == 0) ? wcat : (w == 1) ? wcat + 1024 * 1024
            : (w == 2) ? wcat + 2 * 1024 * 1024 : wob;
    }
    const size_t i = base + threadIdx.x;
    float4 v = ((const float4*)src)[i];
    ushort4 o4;
    o4.x = f2bf(v.x); o4.y = f2bf(v.y); o4.z = f2bf(v.z); o4.w = f2bf(v.w);
    ((ushort4*)dst)[i] = o4;
}

// ---------------- GEMM: C[m][n] = sum_k A[m][k]*B[n][k]  (B^T input) ----------
// MODE 0: QKV fused (N=3072): out = (C + bias[n]) * (n<1024 ? QSCALE : 1).
//   Q,K -> [b][h][s][64] bf16;  V -> TRANSPOSED [b][h][64][s] bf16.
// MODE 1: out-proj (N=1024): OF[m][n] = C + b0[n]  (fp32)
template<int MODE>
__global__ __launch_bounds__(256, 2) void gemm_bt(
    const u16* __restrict__ A, const u16* __restrict__ B,
    const float* __restrict__ b0, const float* __restrict__ b1, const float* __restrict__ b2,
    u16* __restrict__ O0, u16* __restrict__ O1, u16* __restrict__ O2,
    float* __restrict__ OF)
{
    constexpr int K = 1024;
    __shared__ __align__(16) u16 As[128 * 32];
    __shared__ __align__(16) u16 Bs[128 * 32];
    const int tid = threadIdx.x;
    const int wave = tid >> 6, lane = tid & 63;
    const int m0 = blockIdx.y * 128, n0 = blockIdx.x * 128;
    const int wm = (wave >> 1) * 64, wn = (wave & 1) * 64;
    const int fr = lane & 15, fg = lane >> 4;

    f32x4 acc[4][4] = {};

    const int srow = lane >> 2;
    const int scol = (lane & 3) * 8;
    const u16* aSrc = A + (size_t)(m0 + wave * 32 + srow) * K + scol;
    const u16* bSrc = B + (size_t)(n0 + wave * 32 + srow) * K + scol;
    u16* const aDst0 = &As[(wave * 32) * 32];
    u16* const aDst1 = &As[(wave * 32 + 16) * 32];
    u16* const bDst0 = &Bs[(wave * 32) * 32];
    u16* const bDst1 = &Bs[(wave * 32 + 16) * 32];

    for (int kt = 0; kt < K; kt += 32) {
        ASYNC16(aSrc + kt,          aDst0);
        ASYNC16(aSrc + kt + 16 * K, aDst1);
        ASYNC16(bSrc + kt,          bDst0);
        ASYNC16(bSrc + kt + 16 * K, bDst1);
        __syncthreads();
        bf16x8 af[4], bfv[4];
        #pragma unroll
        for (int i = 0; i < 4; ++i) af[i]  = ld8(&As[(wm + i * 16 + fr) * 32 + fg * 8]);
        #pragma unroll
        for (int j = 0; j < 4; ++j) bfv[j] = ld8(&Bs[(wn + j * 16 + fr) * 32 + fg * 8]);
        #pragma unroll
        for (int i = 0; i < 4; ++i)
            #pragma unroll
            for (int j = 0; j < 4; ++j)
                acc[i][j] = __builtin_amdgcn_mfma_f32_16x16x32_bf16(af[i], bfv[j], acc[i][j], 0, 0, 0);
        __syncthreads();
    }

    if constexpr (MODE == 0) {
        const float QSCALE = 0.125f * 1.44269504f;   // 1/sqrt(64) * log2(e)
        #pragma unroll
        for (int j = 0; j < 4; ++j) {
            const int n = n0 + wn + j * 16 + fr;
            const int sel = n >> 10;          // 0=Q 1=K 2=V (uniform per fragment)
            const int w = n & 1023;
            const float bb = (sel == 0 ? b0 : sel == 1 ? b1 : b2)[w];
            const int h = w >> 6, d = w & 63;
            if (sel == 2) {
                // V transposed: Vt[(bi*16+h)*64 + d][s], s-consecutive -> u16x4
                #pragma unroll
                for (int i = 0; i < 4; ++i) {
                    const int m = m0 + wm + i * 16 + fg * 4;   // s base (4-aligned)
                    u16x4 st;
                    #pragma unroll
                    for (int r = 0; r < 4; ++r) st[r] = f2bf(acc[i][j][r] + bb);
                    *(u16x4*)&O2[((size_t)(((m >> 11) * 16 + h) * 64 + d)) * 2048 + (m & 2047)] = st;
                }
            } else {
                const float scale = (sel == 0) ? QSCALE : 1.0f;
                u16* const dst = (sel == 0 ? O0 : O1);
                #pragma unroll
                for (int i = 0; i < 4; ++i) {
                    #pragma unroll
                    for (int r = 0; r < 4; ++r) {
                        const int m = m0 + wm + i * 16 + fg * 4 + r;
                        dst[(((size_t)((m >> 11) * 16 + h) * 2048 + (m & 2047)) << 6) + d] =
                            f2bf((acc[i][j][r] + bb) * scale);
                    }
                }
            }
        }
    } else {
        #pragma unroll
        for (int j = 0; j < 4; ++j) {
            const int n = n0 + wn + j * 16 + fr;
            const float bb = b0[n];
            #pragma unroll
            for (int i = 0; i < 4; ++i) {
                #pragma unroll
                for (int r = 0; r < 4; ++r) {
                    const int m = m0 + wm + i * 16 + fg * 4 + r;
                    OF[(size_t)m * 1024 + n] = acc[i][j][r] + bb;
                }
            }
        }
    }
}

// ---------------- attention kv-loop body (templated on mask usage) ------------
template<bool MASKED>
__device__ __forceinline__ void kv_loop(
    char* smem, const u16* __restrict__ Kbh, const u16* __restrict__ Vtbh,
    const float* __restrict__ mrow, int wave, int fg, int a0, int a1, int t0,
    int srow, int scb, bf16x8 (&qf)[2][2], f32x4 (&o)[4][2], f32x4 (&den)[2],
    const f32x4& FZ, const bf16x8& ONES)
{
    auto STAGE = [&](int buf, int kv0) {
        #pragma unroll
        for (int j = 0; j < 2; ++j) {
            const int r0 = wave * 16 + j * 8;
            const int row = r0 + srow;
            const int sw = scb ^ ((row & 7) << 4);
            ASYNC16((const char*)(Kbh + (size_t)(kv0 + row) * 64) + sw,
                    smem + buf * 8192 + r0 * 128);
            ASYNC16((const char*)(Vtbh + (size_t)row * 2048 + kv0) + sw,
                    smem + 16384 + buf * 8192 + r0 * 128);
        }
    };

    STAGE(0, t0 * 64);
    for (int it = 0; it < 32; it += 2) {
        #pragma unroll
        for (int half = 0; half < 2; ++half) {
            const int tile = (t0 + it + half) & 31;
            const int kv = tile * 64;
            const int kb = half * 8192;            // compile-time dbuf bases
            const int vb = 16384 + half * 8192;
            __syncthreads();                        // buf[half] staged
            if (it + half < 31) STAGE(half ^ 1, ((tile + 1) & 31) * 64);

            float4 mv[4];
            if (MASKED) {
                #pragma unroll
                for (int nj = 0; nj < 4; ++nj)
                    mv[nj] = *(const float4*)(mrow + kv + nj * 16 + fg * 4);
            }

            // per 32-key half: QK -> softmax -> in-reg transpose -> PV
            #pragma unroll
            for (int hh = 0; hh < 2; ++hh) {
                const int aK = hh ? a1 : a0;        // V frag byte-half for this hh
                f32x4 s[2][2];
                #pragma unroll
                for (int njl = 0; njl < 2; ++njl) {
                    const int nj = hh * 2 + njl;
                    bf16x8 k0 = ld8(smem + kb + nj * 2048 + a0);
                    bf16x8 k1 = ld8(smem + kb + nj * 2048 + a1);
                    __builtin_amdgcn_s_setprio(1);
                    #pragma unroll
                    for (int qs = 0; qs < 2; ++qs) {
                        f32x4 z = __builtin_amdgcn_mfma_f32_16x16x32_bf16(k0, qf[qs][0], FZ, 0, 0, 0);
                        s[njl][qs] = __builtin_amdgcn_mfma_f32_16x16x32_bf16(k1, qf[qs][1], z, 0, 0, 0);
                    }
                    __builtin_amdgcn_s_setprio(0);
                }
                // softmax in place: p = exp2(s) [* mask]   (raw-rate v_exp_f32)
                #pragma unroll
                for (int njl = 0; njl < 2; ++njl) {
                    const int nj = hh * 2 + njl;
                    #pragma unroll
                    for (int qs = 0; qs < 2; ++qs)
                        #pragma unroll
                        for (int r = 0; r < 4; ++r) {
                            float p = EXP2(s[njl][qs][r]);
                            if (MASKED) p *= mv[nj][r];
                            s[njl][qs][r] = p;
                        }
                }
                // pack + 4x4 cross-lane transpose -> PV B-operand fragments
                bf16x8 pa[2];
                #pragma unroll
                for (int qs = 0; qs < 2; ++qs) {
                    u32 m0, m1, m2, m3;   // word (W1=njl, W0=r-pair)
                    asm("v_cvt_pk_bf16_f32 %0, %1, %2" : "=v"(m0) : "v"(s[0][qs][0]), "v"(s[0][qs][1]));
                    asm("v_cvt_pk_bf16_f32 %0, %1, %2" : "=v"(m1) : "v"(s[0][qs][2]), "v"(s[0][qs][3]));
                    asm("v_cvt_pk_bf16_f32 %0, %1, %2" : "=v"(m2) : "v"(s[1][qs][0]), "v"(s[1][qs][1]));
                    asm("v_cvt_pk_bf16_f32 %0, %1, %2" : "=v"(m3) : "v"(s[1][qs][2]), "v"(s[1][qs][3]));
                    // step 1: swap(L5, W1); step 2: swap(L4, W1)
                    asm("v_permlane32_swap_b32 %0, %1" : "+v"(m0), "+v"(m2));
                    asm("v_permlane32_swap_b32 %0, %1" : "+v"(m1), "+v"(m3));
                    asm("v_permlane16_swap_b32 %0, %1" : "+v"(m0), "+v"(m2));
                    asm("v_permlane16_swap_b32 %0, %1" : "+v"(m1), "+v"(m3));
                    pa[qs] = __builtin_bit_cast(bf16x8, u32x4{m0, m1, m2, m3});
                }

                // PV + MFMA denominator (row-sum with ONES A-operand)
                __builtin_amdgcn_s_setprio(1);
                #pragma unroll
                for (int qs = 0; qs < 2; ++qs)
                    den[qs] = __builtin_amdgcn_mfma_f32_16x16x32_bf16(ONES, pa[qs], den[qs], 0, 0, 0);
                #pragma unroll
                for (int dj = 0; dj < 4; ++dj) {
                    bf16x8 v = ld8(smem + vb + dj * 2048 + aK);
                    #pragma unroll
                    for (int qs = 0; qs < 2; ++qs)
                        o[dj][qs] = __builtin_amdgcn_mfma_f32_16x16x32_bf16(v, pa[qs], o[dj][qs], 0, 0, 0);
                }
                __builtin_amdgcn_s_setprio(0);
            }
        }
    }
}

// ---------------- flash attention: in-reg P, VALU-lean, mask fast-path --------
// Q [bh][s][64] pre-scaled by 0.125*log2e, K [bh][s][64], Vt [bh][64][s],
// masks [b][s] fp32 (binary), out X2 [b][s][h*64+d] bf16.
// Each wave scans its mask row once; if all == 1.0 the maskless loop variant
// runs (saves 32 muls + 4 VMEM loads per tile; both variants correct for any
// binary mask; branch is wave-uniform and deterministic).
__global__ __launch_bounds__(256, 4) void attn_fwd(
    const u16* __restrict__ Qg, const u16* __restrict__ Kg, const u16* __restrict__ Vt,
    const float* __restrict__ masks, u16* __restrict__ X2)
{
    __shared__ __align__(16) char smem[32768];
    const int tid = threadIdx.x;
    const int wave = tid >> 6, lane = tid & 63;

    // bijective XCD swizzle: 1024 wgs / 8 XCDs -> 128 contiguous wgs (8 bh) per XCD
    const int bidL = blockIdx.x;
    const int wg = ((bidL & 7) << 7) | (bidL >> 3);
    const int bh = wg >> 4;                        // 16 q-blocks per bh
    const int q0 = (wg & 15) * 128 + wave * 32;
    const int b = bh >> 4, h = bh & 15;
    const int fr = lane & 15, fg = lane >> 4;
    const int swz = (fr & 7) << 4;

    // loop-invariant LDS byte addresses
    const int a0 = fr * 128 + ((fg * 16) ^ swz);          // frag low 64B (k/d 0-31)
    const int a1 = fr * 128 + ((64 + fg * 16) ^ swz);     // frag high 64B

    const u16* const Kbh  = Kg + (size_t)bh * 2048 * 64;
    const u16* const Vtbh = Vt + (size_t)bh * 64 * 2048;
    const float* mrow = masks + b * 2048;

    // Q fragments (B-operand): 2 strips of 16 rows
    bf16x8 qf[2][2];
    #pragma unroll
    for (int qs = 0; qs < 2; ++qs) {
        const u16* qp = Qg + ((size_t)bh * 2048 + q0 + qs * 16 + fr) * 64 + fg * 8;
        qf[qs][0] = ld8(qp);
        qf[qs][1] = ld8(qp + 32);
    }

    // wave-uniform all-ones mask check (64 lanes x 8 float4 = 2048 values)
    bool ok = true;
    {
        const float4* mp = (const float4*)mrow;
        #pragma unroll
        for (int i = 0; i < 8; ++i) {
            float4 m = mp[lane + i * 64];
            ok = ok && (m.x == 1.0f) && (m.y == 1.0f) && (m.z == 1.0f) && (m.w == 1.0f);
        }
        ok = __all(ok);
    }

    f32x4 o[4][2] = {};                 // o[dj][qs]: d=dj*16+fg*4+r, q=qs*16+fr
    f32x4 den[2] = {};                  // softmax denominator (all 4 rows identical)
    const f32x4 FZ = {0.f, 0.f, 0.f, 0.f};                 // shared zero C-operand
    const u16x8 ONE_BITS = {0x3F80,0x3F80,0x3F80,0x3F80,0x3F80,0x3F80,0x3F80,0x3F80};
    const bf16x8 ONES = __builtin_bit_cast(bf16x8, ONE_BITS); // bf16 1.0 x8

    const int srow = lane >> 3;
    const int scb = (lane & 7) * 16;

    // co-resident blocks start 8 tiles apart (key order commutes: no-max
    // softmax + linear denominator) -> pipe bursts interleave across blocks
    const int t0 = (((bidL >> 8) & 3) << 3);

    if (ok)
        kv_loop<false>(smem, Kbh, Vtbh, mrow, wave, fg, a0, a1, t0, srow, scb,
                       qf, o, den, FZ, ONES);
    else
        kv_loop<true>(smem, Kbh, Vtbh, mrow, wave, fg, a0, a1, t0, srow, scb,
                      qf, o, den, FZ, ONES);

    // normalize + store (den available in every lane; no cross-lane reduce)
    #pragma unroll
    for (int qs = 0; qs < 2; ++qs) {
        const float inv = 1.0f / den[qs][0];
        const int q = q0 + qs * 16 + fr;
        u16* dst = X2 + ((size_t)(b * 2048 + q)) * 1024 + h * 64 + fg * 4;
        #pragma unroll
        for (int dj = 0; dj < 4; ++dj) {
            u16x4 st;
            #pragma unroll
            for (int r = 0; r < 4; ++r) st[r] = f2bf(o[dj][qs][r] * inv);
            *(u16x4*)(dst + dj * 16) = st;
        }
    }
}

// ---------------- launch ----------------
extern "C" void kernel_launch(void* const* d_in, const int* in_sizes, int n_in,
                              void* d_out, int out_size, void* d_ws, size_t ws_size,
                              hipStream_t stream) {
    const float* query = (const float*)d_in[0];
    const float* masks = (const float*)d_in[1];
    const float* Wq = (const float*)d_in[2];
    const float* bq = (const float*)d_in[3];
    const float* Wk = (const float*)d_in[4];
    const float* bk = (const float*)d_in[5];
    const float* Wv = (const float*)d_in[6];
    const float* bv = (const float*)d_in[7];
    const float* Wo = (const float*)d_in[8];
    const float* bo = (const float*)d_in[9];
    float* out = (float*)d_out;

    // workspace (72 MB):
    //  [ 0,16M): Xb (bf16 query)  -> reused as X2 (attn out) after QKV GEMM
    //  [16,22M): Wcat  [22,24M): Wob
    //  [24,40M): Qg   [40,56M): Kg   [56,72M): Vt (written transposed by GEMM)
    char* ws = (char*)d_ws;
    u16* Xb   = (u16*)(ws);
    u16* Wcat = (u16*)(ws + (16u << 20));
    u16* Wob  = (u16*)(ws + (22u << 20));
    u16* Qg   = (u16*)(ws + (24u << 20));
    u16* Kg   = (u16*)(ws + (40u << 20));
    u16* Vt   = (u16*)(ws + (56u << 20));
    u16* X2   = Xb;   // Xb dead after QKV GEMM

    cvt_all<<<12288, 256, 0, stream>>>(query, Wq, Wk, Wv, Wo, Xb, Wcat, Wob);
    gemm_bt<0><<<dim3(24, 64), 256, 0, stream>>>(Xb, Wcat, bq, bk, bv, Qg, Kg, Vt, nullptr);
    attn_fwd<<<1024, 256, 0, stream>>>(Qg, Kg, Vt, masks, X2);
    gemm_bt<1><<<dim3(8, 64), 256, 0, stream>>>(X2, Wob, bo, nullptr, nullptr, nullptr,
                                                nullptr, nullptr, out);
}